// Round 11
// baseline (229.750 us; speedup 1.0000x reference)
//
#include <hip/hip_runtime.h>
#include <hip/hip_bf16.h>

typedef __attribute__((ext_vector_type(8))) short short8;
typedef __attribute__((ext_vector_type(4))) float f32x4;

#define MFMA16(A, B, C) __builtin_amdgcn_mfma_f32_16x16x32_bf16((A), (B), (C), 0, 0, 0)

#define GL16(gp, lp) __builtin_amdgcn_global_load_lds( \
    (const __attribute__((address_space(1))) void*)(gp), \
    (__attribute__((address_space(3))) void*)(lp), 16, 0, 0)

__device__ __forceinline__ unsigned short bfbits(float f) {
  return __builtin_bit_cast(unsigned short, (__bf16)f);
}

constexpr int BH = 16;
constexpr int Mn = 2048;
constexpr int Dn = 64;
constexpr int LIMn = 2048;
constexpr size_t KF_SHORTS = (size_t)BH * 32 * 8 * 512;
constexpr size_t PE_JROWS = 132;
constexpr size_t PEF_SHORTS = PE_JROWS * 2 * 512;
constexpr int PART_SLOT = 4224;        // 64*64 o + 64 m + 64 l floats
constexpr int SLOTS_PER_HEAD = 72;     // sum of chunks for mt=8..31

__device__ __forceinline__ int part_offs(int mt) {
  return (mt < 16) ? 2 * (mt - 8) : (mt < 24 ? 16 + 3 * (mt - 16) : 40 + 4 * (mt - 24));
}

// ---------------- prep: fp32 -> bf16 MFMA-fragment-tiled layouts (verified r3-r10) ----------------

__global__ void prep_all(const float* __restrict__ K, const float* __restrict__ V,
                         const float* __restrict__ PE,
                         unsigned short* __restrict__ Kf, unsigned short* __restrict__ Vf,
                         unsigned short* __restrict__ PEf) {
  __shared__ float tA[64 * 64];
  __shared__ float tB[64 * 64];
  const int b = blockIdx.x, tid = threadIdx.x;
  const int w = tid >> 6, lane = tid & 63, g = lane >> 4, q15 = lane & 15;

  if (b < 512) {
    const int bh = b >> 5, lt = b & 31;
    const float* Ks = K + ((size_t)bh * Mn + lt * 64) * Dn;
    const float* Vs = V + ((size_t)bh * Mn + lt * 64) * Dn;
    const int row = tid >> 2, c0 = (tid & 3) * 16;
#pragma unroll
    for (int i = 0; i < 4; ++i) {
      *(float4*)&tA[row * 64 + c0 + 4 * i] = ((const float4*)(Ks + (size_t)row * 64 + c0))[i];
      *(float4*)&tB[row * 64 + c0 + 4 * i] = ((const float4*)(Vs + (size_t)row * 64 + c0))[i];
    }
    __syncthreads();
#pragma unroll
    for (int i = 0; i < 2; ++i) {
      const int f = 2 * w + i, nt = f >> 1, s = f & 1;
      short8 uk, uv;
#pragma unroll
      for (int jj = 0; jj < 8; ++jj) {
        uk[jj] = (short)bfbits(tA[(nt * 16 + q15) * 64 + s * 32 + g * 8 + jj]);
        uv[jj] = (short)bfbits(tB[(s * 32 + g * 8 + jj) * 64 + nt * 16 + q15]);
      }
      const size_t base = ((size_t)(bh * 32 + lt) * 8 + f) * 512 + lane * 8;
      *(short8*)&Kf[base] = uk;
      *(short8*)&Vf[base] = uv;
    }
  } else {
    const int pb = b - 512;
    const int c0 = pb * 64;
    const int d = tid >> 2, cc = (tid & 3) * 16;
#pragma unroll
    for (int i = 0; i < 16; ++i) {
      const int cx = c0 + cc + i;
      tA[(cc + i) * 64 + d] = (cx < LIMn) ? PE[(size_t)d * LIMn + cx] : 0.0f;
    }
    __syncthreads();
#pragma unroll
    for (int s = 0; s < 2; ++s) {
      short8 uu;
#pragma unroll
      for (int jj = 0; jj < 8; ++jj)
        uu[jj] = (short)bfbits(tA[(w * 16 + q15) * 64 + s * 32 + g * 8 + jj]);
      *(short8*)&PEf[((size_t)(4 * pb + w) * 2 + s) * 512 + lane * 8] = uu;
    }
  }
}

// ---------------- main: 8-wave blocks, two m-tiles share K/V staging, split-K ----------------

__launch_bounds__(512, 4)
__global__ void stair_main8(const float* __restrict__ Qg,
                            const unsigned short* __restrict__ Kf,
                            const unsigned short* __restrict__ Vf,
                            const unsigned short* __restrict__ PEf,
                            float* __restrict__ Og,
                            float* __restrict__ Part) {
  __shared__ __align__(16) unsigned short Kbuf[2][2][4096];  // [dbuf][pairslot][frags] 32KB
  __shared__ __align__(16) unsigned short Vbuf[2][2][4096];  // 32KB
  __shared__ __align__(16) unsigned short Plds[8][1024];     // per-wave single slot 16KB

  const int tid = threadIdx.x;
  const int w = tid >> 6, lane = tid & 63, g = lane >> 4, q15 = lane & 15;
  const int bid = blockIdx.x;
  const int bh = bid & 15;               // head -> fixed XCD
  const int u = bid >> 4;                // 0..39, heavy-first
  int j, c;
  if (u < 16)      { j = 15 - (u >> 2); c = u & 3; }
  else if (u < 28) { const int v = u - 16; const int q = v / 3; j = 11 - q; c = v - q * 3; }
  else if (u < 36) { const int v = u - 28; j = 7 - (v >> 1); c = v & 1; }
  else             { j = 3 - (u - 36); c = 0; }
  const int ma = 2 * j, mb = ma + 1;     // two adjacent m-tiles per block
  const int t0 = 8 * c;
  const int t1 = (8 * c + 8 < mb + 1) ? (8 * c + 8) : (mb + 1);  // even length always
  const int nch = (mb + 8) >> 3;         // == (ma+8)>>3
  const int w4 = w & 3;
  const int myMt = (w >= 4) ? mb : ma;   // waves 0-3 -> ma, 4-7 -> mb
  const int m0w = myMt * 64 + w4 * 16;
  const int jb0 = 127 - 4 * myMt - w4;

  const float* Qb = Qg + (size_t)bh * Mn * Dn;
  float* Ob = Og + (size_t)bh * Mn * Dn;

  // Q A-fragments
  short8 aq[2];
  {
    const float* qp = Qb + (size_t)(m0w + q15) * Dn;
#pragma unroll
    for (int s = 0; s < 2; ++s) {
      const float4* p = (const float4*)(qp + s * 32 + g * 8);
      float4 f0 = p[0], f1 = p[1];
      short8 a;
      a[0]=(short)bfbits(f0.x); a[1]=(short)bfbits(f0.y); a[2]=(short)bfbits(f0.z); a[3]=(short)bfbits(f0.w);
      a[4]=(short)bfbits(f1.x); a[5]=(short)bfbits(f1.y); a[6]=(short)bfbits(f1.z); a[7]=(short)bfbits(f1.w);
      aq[s] = a;
    }
  }

  float mrun[4], lp[4];                  // lane-partial sums (verified r7-r9)
  f32x4 o[4] = {};
#pragma unroll
  for (int r = 0; r < 4; ++r) { mrun[r] = -1e30f; lp[r] = 0.0f; }

  // stage one tile's K/V frags into (buf, slot): 1 gload_lds each per wave (8 waves = 8 frags)
  auto STAGE1 = [&](int b, int slot, int t) {
    const size_t off = ((size_t)(bh * 32 + t) * 8 + w) * 512 + (size_t)lane * 8;
    GL16(&Kf[off], &Kbuf[b][slot][w * 512]);
    GL16(&Vf[off], &Vbuf[b][slot][w * 512]);
  };

  auto QK = [&](f32x4 qk[4], int cur, int slot, int ntmax) {
#pragma unroll
    for (int s = 0; s < 2; ++s)
#pragma unroll
      for (int nt = 0; nt < 4; ++nt)
        if (nt <= ntmax) {
          short8 bfr = *(const short8*)&Kbuf[cur][slot][(nt * 2 + s) * 512 + lane * 8];
          qk[nt] = MFMA16(aq[s], bfr, qk[nt]);
        }
  };

  // single-shuffle diagonal gather (verified r7-r9)
  auto GATHER = [&](float sv[4][4], const f32x4 qk[4], const f32x4 ev[5],
                    int ntmax, bool diag) {
#pragma unroll
    for (int nt = 0; nt < 4; ++nt)
      if (nt <= ntmax) {
#pragma unroll
        for (int r = 0; r < 4; ++r) {
          const int rw = g * 4 + r;
          const int srcLane = (lane & 48) | ((q15 + 15 - rw) & 15);
          const bool cond = (((q15 + rw + 1) & 15) > rw);
          const float sel = cond ? ev[nt + 1][r] : ev[nt][r];
          const float er = __shfl(sel, srcLane, 64);
          const int li = nt * 16 + q15;
          const bool masked = diag && (li > w4 * 16 + rw);
          sv[nt][r] = masked ? -1e30f : (qk[nt][r] + er) * 0.125f;
        }
      }
  };

  // P bounce (single per-wave slot, same-wave in-order) + PV
  auto PV = [&](const float sv[4][4], int cur, int slot, int smax) {
#pragma unroll
    for (int nt = 0; nt < 4; ++nt)
#pragma unroll
      for (int r = 0; r < 4; ++r) {
        const int rw = g * 4 + r;
        Plds[w][(rw * 64 + nt * 16 + q15) ^ ((rw & 7) << 3)] = bfbits(sv[nt][r]);
      }
    short8 pa[2];
#pragma unroll
    for (int s = 0; s < 2; ++s)
      if (s <= smax)
        pa[s] = *(short8*)&Plds[w][(q15 * 64 + s * 32 + g * 8) ^ ((q15 & 7) << 3)];
#pragma unroll
    for (int s = 0; s < 2; ++s)
      if (s <= smax)
#pragma unroll
        for (int nt = 0; nt < 4; ++nt) {
          short8 bfr = *(const short8*)&Vbuf[cur][slot][(nt * 2 + s) * 512 + lane * 8];
          o[nt] = MFMA16(pa[s], bfr, o[nt]);
        }
  };

  // ---- pair body over 128 cols; per-half masks (A-diag: lower, B-diag: upper) ----
  auto PAIR = [&](int t, int cur) {
    const int tB = t + 1;
    const bool diagA = (t == myMt);            // only lower half (myMt even == t even)
    const bool actB  = (tB <= myMt);
    const bool diagB = (tB == myMt);           // only upper half
    const int ntmaxA = diagA ? w4 : 3;
    const int smaxA  = diagA ? (w4 >> 1) : 1;
    const int ntmaxB = actB ? (diagB ? w4 : 3) : -1;
    const int u5B    = actB ? (diagB ? (w4 + 2) : 5) : 0;
    const int smaxB  = actB ? (diagB ? (w4 >> 1) : 1) : -1;
    const int jbA = jb0 + 4 * t;
    const int jbB = jbA + 4;

    // PE loads early (L2-hot); A loads all 5 (safe over-read into zero pad)
    short8 peA[2][5], peB[2][5];
#pragma unroll
    for (int s = 0; s < 2; ++s)
#pragma unroll
      for (int uu = 0; uu < 5; ++uu) {
        peA[s][uu] = *(const short8*)&PEf[((size_t)(jbA + uu) * 2 + s) * 512 + lane * 8];
        if (uu < u5B)
          peB[s][uu] = *(const short8*)&PEf[((size_t)(jbB + uu) * 2 + s) * 512 + lane * 8];
      }

    f32x4 qkA[4] = {}, qkB[4] = {};
    QK(qkA, cur, 0, ntmaxA);
    QK(qkB, cur, 1, ntmaxB);

    f32x4 evA[5] = {};
#pragma unroll
    for (int s = 0; s < 2; ++s)
#pragma unroll
      for (int uu = 0; uu < 5; ++uu) evA[uu] = MFMA16(aq[s], peA[s][uu], evA[uu]);

    float svA[4][4], svB[4][4];
#pragma unroll
    for (int nt = 0; nt < 4; ++nt)
#pragma unroll
      for (int r = 0; r < 4; ++r) { svA[nt][r] = -1e30f; svB[nt][r] = -1e30f; }

    GATHER(svA, qkA, evA, ntmaxA, diagA);

    f32x4 evB[5] = {};
#pragma unroll
    for (int s = 0; s < 2; ++s)
#pragma unroll
      for (int uu = 0; uu < 5; ++uu)
        if (uu < u5B) evB[uu] = MFMA16(aq[s], peB[s][uu], evB[uu]);

    GATHER(svB, qkB, evB, ntmaxB, diagB);

    // joint defer-max online softmax over 128 cols (lane-partial sums)
    float lmax[4];
#pragma unroll
    for (int r = 0; r < 4; ++r) {
      float a = fmaxf(fmaxf(svA[0][r], svA[1][r]), fmaxf(svA[2][r], svA[3][r]));
      float b = fmaxf(fmaxf(svB[0][r], svB[1][r]), fmaxf(svB[2][r], svB[3][r]));
      lmax[r] = fmaxf(a, b);
    }
    const bool fast = __all((lmax[0] <= mrun[0] + 8.f) & (lmax[1] <= mrun[1] + 8.f) &
                            (lmax[2] <= mrun[2] + 8.f) & (lmax[3] <= mrun[3] + 8.f));
    if (!fast) {
#pragma unroll
      for (int r = 0; r < 4; ++r) {
        float mx = lmax[r];
        mx = fmaxf(mx, __shfl_xor(mx, 1));
        mx = fmaxf(mx, __shfl_xor(mx, 2));
        mx = fmaxf(mx, __shfl_xor(mx, 4));
        mx = fmaxf(mx, __shfl_xor(mx, 8));
        const float mn = fmaxf(mrun[r], mx);
        const float alpha = exp2f((mrun[r] - mn) * 1.44269504f);
        mrun[r] = mn;
        lp[r] *= alpha;
        o[0][r] *= alpha; o[1][r] *= alpha; o[2][r] *= alpha; o[3][r] *= alpha;
      }
    }
#pragma unroll
    for (int nt = 0; nt < 4; ++nt)
#pragma unroll
      for (int r = 0; r < 4; ++r) {
        svA[nt][r] = exp2f((svA[nt][r] - mrun[r]) * 1.44269504f);
        svB[nt][r] = exp2f((svB[nt][r] - mrun[r]) * 1.44269504f);
      }
#pragma unroll
    for (int r = 0; r < 4; ++r)
      lp[r] += ((svA[0][r] + svA[1][r]) + (svA[2][r] + svA[3][r])) +
               ((svB[0][r] + svB[1][r]) + (svB[2][r] + svB[3][r]));

    PV(svA, cur, 0, smaxA);
    PV(svB, cur, 1, smaxB);
  };

  // ---- main loop: pure pairs (chunk lengths always even), one barrier per pair ----
  {
    int cur = 0;
    STAGE1(0, 0, t0);
    STAGE1(0, 1, t0 + 1);
    __syncthreads();
    for (int t = t0; t < t1; t += 2) {
      const bool more = (t + 2 < t1);
      if (more) {
        STAGE1(cur ^ 1, 0, t + 2);
        STAGE1(cur ^ 1, 1, t + 3);
      }
      PAIR(t, cur);
      if (more) __syncthreads();
      cur ^= 1;
    }
  }

  // ---- epilogue: one-time butterfly of lane-partial sums ----
  float lr[4];
#pragma unroll
  for (int r = 0; r < 4; ++r) {
    float s = lp[r];
    s += __shfl_xor(s, 1);
    s += __shfl_xor(s, 2);
    s += __shfl_xor(s, 4);
    s += __shfl_xor(s, 8);
    lr[r] = s;
  }

  if (nch == 1) {
#pragma unroll
    for (int nt = 0; nt < 4; ++nt)
#pragma unroll
      for (int r = 0; r < 4; ++r) {
        const int m = m0w + g * 4 + r;
        Ob[(size_t)m * Dn + nt * 16 + q15] = o[nt][r] / lr[r];
      }
  } else {
    float* ps = Part + ((size_t)bh * SLOTS_PER_HEAD + part_offs(myMt) + c) * PART_SLOT;
#pragma unroll
    for (int nt = 0; nt < 4; ++nt)
#pragma unroll
      for (int r = 0; r < 4; ++r)
        ps[(w4 * 16 + g * 4 + r) * 64 + nt * 16 + q15] = o[nt][r];
#pragma unroll
    for (int r = 0; r < 4; ++r)
      if (q15 == g * 4 + r) {
        ps[4096 + w4 * 16 + q15] = mrun[r];
        ps[4160 + w4 * 16 + q15] = lr[r];
      }
  }
}

// ---------------- combine: merge 2-4 chunk partials per (head, mtile>=8) ----------------

__launch_bounds__(256, 4)
__global__ void combine_parts(const float* __restrict__ Part, float* __restrict__ Og) {
  const int bid = blockIdx.x;
  const int bh = bid & 15;
  const int mt = 8 + (bid >> 4);
  const int nch = (mt + 8) >> 3;
  const float* base = Part + ((size_t)bh * SLOTS_PER_HEAD + part_offs(mt)) * PART_SLOT;
  const int tid = threadIdx.x;
  const int row = tid >> 2;
  const int qc = (tid & 3) * 16;

  float mstar = -1e30f;
#pragma unroll
  for (int cc = 0; cc < 4; ++cc)
    if (cc < nch) mstar = fmaxf(mstar, base[cc * PART_SLOT + 4096 + row]);
  float lsum = 0.f;
  f32x4 acc0 = {}, acc1 = {}, acc2 = {}, acc3 = {};
#pragma unroll
  for (int cc = 0; cc < 4; ++cc)
    if (cc < nch) {
      const float* ps = base + cc * PART_SLOT;
      const float sc = exp2f((ps[4096 + row] - mstar) * 1.44269504f);
      lsum += ps[4160 + row] * sc;
      const f32x4* op = (const f32x4*)&ps[row * 64 + qc];
      acc0 += op[0] * sc; acc1 += op[1] * sc; acc2 += op[2] * sc; acc3 += op[3] * sc;
    }
  const float inv = 1.f / lsum;
  float* dst = Og + ((size_t)bh * Mn + mt * 64 + row) * Dn + qc;
  *(f32x4*)&dst[0]  = acc0 * inv;
  *(f32x4*)&dst[4]  = acc1 * inv;
  *(f32x4*)&dst[8]  = acc2 * inv;
  *(f32x4*)&dst[12] = acc3 * inv;
}

// ---------------- r9 mono main (fallback when ws holds only frag buffers) ----------------

__launch_bounds__(256)
__global__ void stair_main(const float* __restrict__ Qg,
                           const unsigned short* __restrict__ Kf,
                           const unsigned short* __restrict__ Vf,
                           const unsigned short* __restrict__ PEf,
                           float* __restrict__ Og) {
  __shared__ __align__(16) unsigned short Kbuf[2][2][4096];
  __shared__ __align__(16) unsigned short Vbuf[2][2][4096];
  __shared__ __align__(16) unsigned short Plds[4][2048];

  const int tid = threadIdx.x;
  const int w = tid >> 6, lane = tid & 63, g = lane >> 4, q15 = lane & 15;
  const int bid = blockIdx.x;
  const int bh = bid & 15;
  const int mt = 31 - (bid >> 4);
  const int t0 = 0, t1 = mt + 1;
  const int m0w = mt * 64 + w * 16;
  const int jb0 = 127 - 4 * mt - w;

  const float* Qb = Qg + (size_t)bh * Mn * Dn;
  float* Ob = Og + (size_t)bh * Mn * Dn;

  short8 aq[2];
  {
    const float* qp = Qb + (size_t)(m0w + q15) * Dn;
#pragma unroll
    for (int s = 0; s < 2; ++s) {
      const float4* p = (const float4*)(qp + s * 32 + g * 8);
      float4 f0 = p[0], f1 = p[1];
      short8 a;
      a[0]=(short)bfbits(f0.x); a[1]=(short)bfbits(f0.y); a[2]=(short)bfbits(f0.z); a[3]=(short)bfbits(f0.w);
      a[4]=(short)bfbits(f1.x); a[5]=(short)bfbits(f1.y); a[6]=(short)bfbits(f1.z); a[7]=(short)bfbits(f1.w);
      aq[s] = a;
    }
  }

  float mrun[4], lp[4];
  f32x4 o[4] = {};
#pragma unroll
  for (int r = 0; r < 4; ++r) { mrun[r] = -1e30f; lp[r] = 0.0f; }

  auto STAGE1 = [&](int b, int slot, int t) {
    const size_t toff = ((size_t)(bh * 32 + t) * 8) * 512;
#pragma unroll
    for (int i = 0; i < 2; ++i) {
      const int f = 2 * w + i;
      const size_t off = toff + (size_t)f * 512 + lane * 8;
      GL16(&Kf[off], &Kbuf[b][slot][f * 512]);
      GL16(&Vf[off], &Vbuf[b][slot][f * 512]);
    }
  };

  auto QK = [&](f32x4 qk[4], int cur, int slot, int ntmax) {
#pragma unroll
    for (int s = 0; s < 2; ++s)
#pragma unroll
      for (int nt = 0; nt < 4; ++nt)
        if (nt <= ntmax) {
          short8 bfr = *(const short8*)&Kbuf[cur][slot][(nt * 2 + s) * 512 + lane * 8];
          qk[nt] = MFMA16(aq[s], bfr, qk[nt]);
        }
  };

  auto GATHER = [&](float sv[4][4], const f32x4 qk[4], const f32x4 ev[5],
                    int ntmax, bool diag) {
#pragma unroll
    for (int nt = 0; nt < 4; ++nt)
      if (nt <= ntmax) {
#pragma unroll
        for (int r = 0; r < 4; ++r) {
          const int rw = g * 4 + r;
          const int srcLane = (lane & 48) | ((q15 + 15 - rw) & 15);
          const bool cond = (((q15 + rw + 1) & 15) > rw);
          const float sel = cond ? ev[nt + 1][r] : ev[nt][r];
          const float er = __shfl(sel, srcLane, 64);
          const int li = nt * 16 + q15;
          const bool masked = diag && (li > w * 16 + rw);
          sv[nt][r] = masked ? -1e30f : (qk[nt][r] + er) * 0.125f;
        }
      }
  };

  auto PV = [&](const float sv[4][4], int cur, int slot, int smax) {
#pragma unroll
    for (int nt = 0; nt < 4; ++nt)
#pragma unroll
      for (int r = 0; r < 4; ++r) {
        const int rw = g * 4 + r;
        Plds[w][slot * 1024 + ((rw * 64 + nt * 16 + q15) ^ ((rw & 7) << 3))] = bfbits(sv[nt][r]);
      }
    short8 pa[2];
#pragma unroll
    for (int s = 0; s < 2; ++s)
      if (s <= smax)
        pa[s] = *(short8*)&Plds[w][slot * 1024 + ((q15 * 64 + s * 32 + g * 8) ^ ((q15 & 7) << 3))];
#pragma unroll
    for (int s = 0; s < 2; ++s)
      if (s <= smax)
#pragma unroll
        for (int nt = 0; nt < 4; ++nt) {
          short8 bfr = *(const short8*)&Vbuf[cur][slot][(nt * 2 + s) * 512 + lane * 8];
          o[nt] = MFMA16(pa[s], bfr, o[nt]);
        }
  };

  auto PAIR = [&](int t, int cur, bool diagB) {
    const int jbA = jb0 + 4 * t;
    const int jbB = jbA + 4;
    const int ntmaxB = diagB ? w : 3;
    const int u5B = diagB ? (w + 2) : 5;
    const int smaxB = diagB ? (w >> 1) : 1;

    short8 peA[2][5], peB[2][5];
#pragma unroll
    for (int s = 0; s < 2; ++s)
#pragma unroll
      for (int uu = 0; uu < 5; ++uu) {
        peA[s][uu] = *(const short8*)&PEf[((size_t)(jbA + uu) * 2 + s) * 512 + lane * 8];
        if (uu < u5B)
          peB[s][uu] = *(const short8*)&PEf[((size_t)(jbB + uu) * 2 + s) * 512 + lane * 8];
      }

    f32x4 qkA[4] = {}, qkB[4] = {};
    QK(qkA, cur, 0, 3);
    QK(qkB, cur, 1, ntmaxB);

    f32x4 evA[5] = {};
#pragma unroll
    for (int s = 0; s < 2; ++s)
#pragma unroll
      for (int uu = 0; uu < 5; ++uu) evA[uu] = MFMA16(aq[s], peA[s][uu], evA[uu]);

    float svA[4][4], svB[4][4];
#pragma unroll
    for (int nt = 0; nt < 4; ++nt)
#pragma unroll
      for (int r = 0; r < 4; ++r) { svA[nt][r] = -1e30f; svB[nt][r] = -1e30f; }

    GATHER(svA, qkA, evA, 3, false);

    f32x4 evB[5] = {};
#pragma unroll
    for (int s = 0; s < 2; ++s)
#pragma unroll
      for (int uu = 0; uu < 5; ++uu)
        if (uu < u5B) evB[uu] = MFMA16(aq[s], peB[s][uu], evB[uu]);

    GATHER(svB, qkB, evB, ntmaxB, diagB);

    float lmax[4];
#pragma unroll
    for (int r = 0; r < 4; ++r) {
      float a = fmaxf(fmaxf(svA[0][r], svA[1][r]), fmaxf(svA[2][r], svA[3][r]));
      float b = fmaxf(fmaxf(svB[0][r], svB[1][r]), fmaxf(svB[2][r], svB[3][r]));
      lmax[r] = fmaxf(a, b);
    }
    const bool fast = __all((lmax[0] <= mrun[0] + 8.f) & (lmax[1] <= mrun[1] + 8.f) &
                            (lmax[2] <= mrun[2] + 8.f) & (lmax[3] <= mrun[3] + 8.f));
    if (!fast) {
#pragma unroll
      for (int r = 0; r < 4; ++r) {
        float mx = lmax[r];
        mx = fmaxf(mx, __shfl_xor(mx, 1));
        mx = fmaxf(mx, __shfl_xor(mx, 2));
        mx = fmaxf(mx, __shfl_xor(mx, 4));
        mx = fmaxf(mx, __shfl_xor(mx, 8));
        const float mn = fmaxf(mrun[r], mx);
        const float alpha = exp2f((mrun[r] - mn) * 1.44269504f);
        mrun[r] = mn;
        lp[r] *= alpha;
        o[0][r] *= alpha; o[1][r] *= alpha; o[2][r] *= alpha; o[3][r] *= alpha;
      }
    }
#pragma unroll
    for (int nt = 0; nt < 4; ++nt)
#pragma unroll
      for (int r = 0; r < 4; ++r) {
        svA[nt][r] = exp2f((svA[nt][r] - mrun[r]) * 1.44269504f);
        svB[nt][r] = exp2f((svB[nt][r] - mrun[r]) * 1.44269504f);
      }
#pragma unroll
    for (int r = 0; r < 4; ++r)
      lp[r] += ((svA[0][r] + svA[1][r]) + (svA[2][r] + svA[3][r])) +
               ((svB[0][r] + svB[1][r]) + (svB[2][r] + svB[3][r]));

    PV(svA, cur, 0, 1);
    PV(svB, cur, 1, smaxB);
  };

  auto SINGLE = [&](int t, int cur, bool diag) {
    const int jb = jb0 + 4 * t;
    const int ntmax = diag ? w : 3;
    const int u5 = diag ? (w + 2) : 5;
    const int smax = diag ? (w >> 1) : 1;

    short8 pe[2][5];
#pragma unroll
    for (int s = 0; s < 2; ++s)
#pragma unroll
      for (int uu = 0; uu < 5; ++uu)
        if (uu < u5)
          pe[s][uu] = *(const short8*)&PEf[((size_t)(jb + uu) * 2 + s) * 512 + lane * 8];

    f32x4 qk[4] = {};
    QK(qk, cur, 0, ntmax);
    f32x4 ev[5] = {};
#pragma unroll
    for (int s = 0; s < 2; ++s)
#pragma unroll
      for (int uu = 0; uu < 5; ++uu)
        if (uu < u5) ev[uu] = MFMA16(aq[s], pe[s][uu], ev[uu]);

    float sv[4][4];
#pragma unroll
    for (int nt = 0; nt < 4; ++nt)
#pragma unroll
      for (int r = 0; r < 4; ++r) sv[nt][r] = -1e30f;
    GATHER(sv, qk, ev, ntmax, diag);

    float lmax[4];
#pragma unroll
    for (int r = 0; r < 4; ++r)
      lmax[r] = fmaxf(fmaxf(sv[0][r], sv[1][r]), fmaxf(sv[2][r], sv[3][r]));
    const bool fast = __all((lmax[0] <= mrun[0] + 8.f) & (lmax[1] <= mrun[1] + 8.f) &
                            (lmax[2] <= mrun[2] + 8.f) & (lmax[3] <= mrun[3] + 8.f));
    if (!fast) {
#pragma unroll
      for (int r = 0; r < 4; ++r) {
        float mx = lmax[r];
        mx = fmaxf(mx, __shfl_xor(mx, 1));
        mx = fmaxf(mx, __shfl_xor(mx, 2));
        mx = fmaxf(mx, __shfl_xor(mx, 4));
        mx = fmaxf(mx, __shfl_xor(mx, 8));
        const float mn = fmaxf(mrun[r], mx);
        const float alpha = exp2f((mrun[r] - mn) * 1.44269504f);
        mrun[r] = mn;
        lp[r] *= alpha;
        o[0][r] *= alpha; o[1][r] *= alpha; o[2][r] *= alpha; o[3][r] *= alpha;
      }
    }
#pragma unroll
    for (int nt = 0; nt < 4; ++nt)
#pragma unroll
      for (int r = 0; r < 4; ++r)
        sv[nt][r] = exp2f((sv[nt][r] - mrun[r]) * 1.44269504f);
#pragma unroll
    for (int r = 0; r < 4; ++r)
      lp[r] += (sv[0][r] + sv[1][r]) + (sv[2][r] + sv[3][r]);
    PV(sv, cur, 0, smax);
  };

  {
    int cur = 0;
    int t = t0;
    const int n0 = (t1 - t0 >= 2) ? 2 : 1;
    STAGE1(0, 0, t0);
    if (n0 == 2) STAGE1(0, 1, t0 + 1);
    __syncthreads();
    while (t < t1) {
      const int n = (t1 - t >= 2) ? 2 : 1;
      const int rem = t1 - (t + n);
      const int nn = (rem >= 2) ? 2 : rem;
      if (nn > 0) {
        STAGE1(cur ^ 1, 0, t + n);
        if (nn == 2) STAGE1(cur ^ 1, 1, t + n + 1);
      }
      if (n == 2) PAIR(t, cur, (t + 1 == mt));
      else SINGLE(t, cur, (t == mt));
      if (nn > 0) __syncthreads();
      cur ^= 1;
      t += n;
    }
  }

  float lr[4];
#pragma unroll
  for (int r = 0; r < 4; ++r) {
    float s = lp[r];
    s += __shfl_xor(s, 1);
    s += __shfl_xor(s, 2);
    s += __shfl_xor(s, 4);
    s += __shfl_xor(s, 8);
    lr[r] = s;
  }

#pragma unroll
  for (int nt = 0; nt < 4; ++nt)
#pragma unroll
    for (int r = 0; r < 4; ++r) {
      const int m = m0w + g * 4 + r;
      Ob[(size_t)m * Dn + nt * 16 + q15] = o[nt][r] / lr[r];
    }
}

// ---------------- fallback (round-1 kernel, passed @118us, no ws needed) ----------------

constexpr int ESTRIDE = 84;

__launch_bounds__(256, 2)
__global__ void stair_attn_fb(const float* __restrict__ Qg,
                              const float* __restrict__ Kg,
                              const float* __restrict__ Vg,
                              const float* __restrict__ PEg,
                              float* __restrict__ Og) {
  __shared__ __align__(16) unsigned short Kb[64 * 64];
  __shared__ __align__(16) unsigned short Vt[64 * 64];
  __shared__ __align__(16) unsigned short Pb[128 * 64];
  __shared__ __align__(16) float Elds[4 * 16 * ESTRIDE];
  __shared__ __align__(16) unsigned short Plds[4 * 16 * 64];

  const int tid = threadIdx.x;
  const int w = tid >> 6;
  const int lane = tid & 63;
  const int g = lane >> 4;
  const int q15 = lane & 15;

  const int bid = blockIdx.x;
  const int bh = bid & 15;
  const int jid = bid >> 4;
  const int mt = (jid < 16) ? (2 * jid) : (63 - 2 * jid);
  const int m0 = mt * 64;

  const float* Qb = Qg + (size_t)bh * Mn * Dn;
  const float* Kbase = Kg + (size_t)bh * Mn * Dn;
  const float* Vbase = Vg + (size_t)bh * Mn * Dn;
  float* Ob = Og + (size_t)bh * Mn * Dn;

  short8 aq[2];
  {
    const float* qp = Qb + (size_t)(m0 + 16 * w + q15) * Dn;
#pragma unroll
    for (int s = 0; s < 2; ++s) {
      const float4* p = (const float4*)(qp + s * 32 + g * 8);
      float4 f0 = p[0], f1 = p[1];
      short8 a;
      a[0]=(short)bfbits(f0.x); a[1]=(short)bfbits(f0.y); a[2]=(short)bfbits(f0.z); a[3]=(short)bfbits(f0.w);
      a[4]=(short)bfbits(f1.x); a[5]=(short)bfbits(f1.y); a[6]=(short)bfbits(f1.z); a[7]=(short)bfbits(f1.w);
      aq[s] = a;
    }
  }

  float mrun[4], lrun[4];
  f32x4 o[4] = {};
#pragma unroll
  for (int r = 0; r < 4; ++r) { mrun[r] = -1e30f; lrun[r] = 0.0f; }

  const int ntiles = mt + 1;
  const int dso = g * 8;

  for (int t = 0; t < ntiles; ++t) {
    const int l0 = t * 64;
    __syncthreads();
    {
      const int l = tid >> 2;
      const int dq = (tid & 3) * 16;
      const float* kp = Kbase + (size_t)(l0 + l) * Dn + dq;
      short8 u0, u1;
      {
        float4 f = ((const float4*)kp)[0];
        u0[0]=(short)bfbits(f.x); u0[1]=(short)bfbits(f.y); u0[2]=(short)bfbits(f.z); u0[3]=(short)bfbits(f.w);
        f = ((const float4*)kp)[1];
        u0[4]=(short)bfbits(f.x); u0[5]=(short)bfbits(f.y); u0[6]=(short)bfbits(f.z); u0[7]=(short)bfbits(f.w);
        f = ((const float4*)kp)[2];
        u1[0]=(short)bfbits(f.x); u1[1]=(short)bfbits(f.y); u1[2]=(short)bfbits(f.z); u1[3]=(short)bfbits(f.w);
        f = ((const float4*)kp)[3];
        u1[4]=(short)bfbits(f.x); u1[5]=(short)bfbits(f.y); u1[6]=(short)bfbits(f.z); u1[7]=(short)bfbits(f.w);
      }
      const int swz = (l & 7) << 3;
      *(short8*)&Kb[(l * 64 + dq) ^ swz] = u0;
      *(short8*)&Kb[(l * 64 + dq + 8) ^ swz] = u1;
    }
    {
      const int lrow = lane;
      const int ds = w * 16;
      const float* vp = Vbase + (size_t)(l0 + lrow) * Dn + ds;
#pragma unroll
      for (int i = 0; i < 4; ++i) {
        float4 f = ((const float4*)vp)[i];
        int c0 = ds + 4 * i;
        Vt[((c0 + 0) * 64 + lrow) ^ (((c0 + 0) & 7) << 3)] = bfbits(f.x);
        Vt[((c0 + 1) * 64 + lrow) ^ (((c0 + 1) & 7) << 3)] = bfbits(f.y);
        Vt[((c0 + 2) * 64 + lrow) ^ (((c0 + 2) & 7) << 3)] = bfbits(f.z);
        Vt[((c0 + 3) * 64 + lrow) ^ (((c0 + 3) & 7) << 3)] = bfbits(f.w);
      }
    }
    {
      const int d = lane;
      const int cc = w * 32;
      const int cb = (2048 - 64) - m0 + l0;
      const float* pp = PEg + (size_t)d * LIMn + (cb + cc);
      if (cb + cc + 31 < LIMn) {
#pragma unroll
        for (int i = 0; i < 8; ++i) {
          float4 f = ((const float4*)pp)[i];
          int c0 = cc + 4 * i;
          Pb[((c0 + 0) * 64 + d) ^ (((c0 + 0) & 7) << 3)] = bfbits(f.x);
          Pb[((c0 + 1) * 64 + d) ^ (((c0 + 1) & 7) << 3)] = bfbits(f.y);
          Pb[((c0 + 2) * 64 + d) ^ (((c0 + 2) & 7) << 3)] = bfbits(f.z);
          Pb[((c0 + 3) * 64 + d) ^ (((c0 + 3) & 7) << 3)] = bfbits(f.w);
        }
      } else {
        for (int i = 0; i < 32; ++i) {
          int cabs = cb + cc + i;
          float f = (cabs < LIMn) ? pp[i] : 0.0f;
          int c0 = cc + i;
          Pb[(c0 * 64 + d) ^ ((c0 & 7) << 3)] = bfbits(f);
        }
      }
    }
    __syncthreads();

    f32x4 qk[4] = {};
#pragma unroll
    for (int s = 0; s < 2; ++s)
#pragma unroll
      for (int nt = 0; nt < 4; ++nt) {
        int l = nt * 16 + q15;
        short8 b = *(short8*)&Kb[(l * 64 + s * 32 + dso) ^ ((l & 7) << 3)];
        qk[nt] = MFMA16(aq[s], b, qk[nt]);
      }

    f32x4 ev[5] = {};
    const int ntb = 3 - w;
#pragma unroll
    for (int s = 0; s < 2; ++s)
#pragma unroll
      for (int u5 = 0; u5 < 5; ++u5) {
        int c = (ntb + u5) * 16 + q15;
        short8 b = *(short8*)&Pb[(c * 64 + s * 32 + dso) ^ ((c & 7) << 3)];
        ev[u5] = MFMA16(aq[s], b, ev[u5]);
      }
    float* Ew = Elds + w * 16 * ESTRIDE;
#pragma unroll
    for (int u5 = 0; u5 < 5; ++u5)
#pragma unroll
      for (int r = 0; r < 4; ++r)
        Ew[(g * 4 + r) * ESTRIDE + u5 * 16 + q15] = ev[u5][r];

    const bool diag = (t == ntiles - 1);
    float sv[4][4];
#pragma unroll
    for (int nt = 0; nt < 4; ++nt) {
      int li = nt * 16 + q15;
#pragma unroll
      for (int r = 0; r < 4; ++r) {
        int rw = g * 4 + r;
        float eread = Ew[rw * ESTRIDE + (15 - rw + li)];
        bool masked = diag && (li > (16 * w + rw));
        sv[nt][r] = masked ? -1e30f : (qk[nt][r] + eread) * 0.125f;
      }
    }

    float mnew[4], alpha[4];
#pragma unroll
    for (int r = 0; r < 4; ++r) {
      float mx = fmaxf(fmaxf(sv[0][r], sv[1][r]), fmaxf(sv[2][r], sv[3][r]));
      mx = fmaxf(mx, __shfl_xor(mx, 1));
      mx = fmaxf(mx, __shfl_xor(mx, 2));
      mx = fmaxf(mx, __shfl_xor(mx, 4));
      mx = fmaxf(mx, __shfl_xor(mx, 8));
      float mn = fmaxf(mrun[r], mx);
      alpha[r] = exp2f((mrun[r] - mn) * 1.44269504f);
      mnew[r] = mn;
      mrun[r] = mn;
    }
    float pexp[4][4];
#pragma unroll
    for (int nt = 0; nt < 4; ++nt)
#pragma unroll
      for (int r = 0; r < 4; ++r)
        pexp[nt][r] = exp2f((sv[nt][r] - mnew[r]) * 1.44269504f);
#pragma unroll
    for (int r = 0; r < 4; ++r) {
      float sum = (pexp[0][r] + pexp[1][r]) + (pexp[2][r] + pexp[3][r]);
      sum += __shfl_xor(sum, 1);
      sum += __shfl_xor(sum, 2);
      sum += __shfl_xor(sum, 4);
      sum += __shfl_xor(sum, 8);
      lrun[r] = lrun[r] * alpha[r] + sum;
      o[0][r] *= alpha[r];
      o[1][r] *= alpha[r];
      o[2][r] *= alpha[r];
      o[3][r] *= alpha[r];
    }

    unsigned short* Pw = Plds + w * 16 * 64;
#pragma unroll
    for (int nt = 0; nt < 4; ++nt)
#pragma unroll
      for (int r = 0; r < 4; ++r) {
        int rw = g * 4 + r;
        Pw[(rw * 64 + nt * 16 + q15) ^ ((rw & 7) << 3)] = bfbits(pexp[nt][r]);
      }
    short8 pa[2];
#pragma unroll
    for (int s = 0; s < 2; ++s)
      pa[s] = *(short8*)&Pw[(q15 * 64 + s * 32 + dso) ^ ((q15 & 7) << 3)];

#pragma unroll
    for (int s = 0; s < 2; ++s)
#pragma unroll
      for (int nt = 0; nt < 4; ++nt) {
        int d = nt * 16 + q15;
        short8 b = *(short8*)&Vt[(d * 64 + s * 32 + dso) ^ ((d & 7) << 3)];
        o[nt] = MFMA16(pa[s], b, o[nt]);
      }
  }

#pragma unroll
  for (int nt = 0; nt < 4; ++nt)
#pragma unroll
    for (int r = 0; r < 4; ++r) {
      int m = m0 + 16 * w + g * 4 + r;
      Ob[(size_t)m * Dn + nt * 16 + q15] = o[nt][r] / lrun[r];
    }
}

// ---------------- launch ----------------

extern "C" void kernel_launch(void* const* d_in, const int* in_sizes, int n_in,
                              void* d_out, int out_size, void* d_ws, size_t ws_size,
                              hipStream_t stream) {
  (void)in_sizes; (void)n_in; (void)out_size;
  const float* Q  = (const float*)d_in[0];
  const float* K  = (const float*)d_in[1];
  const float* V  = (const float*)d_in[2];
  const float* PE = (const float*)d_in[3];
  float* Out = (float*)d_out;

  const size_t szK = KF_SHORTS * sizeof(unsigned short);              // 4 MB
  const size_t szV = szK;                                              // 4 MB
  const size_t szP = PEF_SHORTS * sizeof(unsigned short);              // 264 KB
  const size_t szPart = (size_t)BH * SLOTS_PER_HEAD * PART_SLOT * 4;   // 19.5 MB
  const size_t need1 = szK + szV + szP;
  const size_t need2 = need1 + szPart;

  if (ws_size >= need1) {
    unsigned short* Kf  = (unsigned short*)d_ws;
    unsigned short* Vf  = (unsigned short*)((char*)d_ws + szK);
    unsigned short* PEf = (unsigned short*)((char*)d_ws + szK + szV);
    float* Part = (float*)((char*)d_ws + need1);

    hipLaunchKernelGGL(prep_all, dim3(512 + 33), dim3(256), 0, stream, K, V, PE, Kf, Vf, PEf);
    if (ws_size >= need2) {
      hipLaunchKernelGGL(stair_main8, dim3(BH * 40), dim3(512), 0, stream,
                         Q, Kf, Vf, PEf, Out, Part);
      hipLaunchKernelGGL(combine_parts, dim3(BH * 24), dim3(256), 0, stream, Part, Out);
    } else {
      hipLaunchKernelGGL(stair_main, dim3(512), dim3(256), 0, stream,
                         Q, Kf, Vf, PEf, Out);
    }
  } else {
    hipLaunchKernelGGL(stair_attn_fb, dim3(512), dim3(256), 0, stream, Q, K, V, PE, Out);
  }
}

// Round 12
// 66.872 us; speedup vs baseline: 3.4356x; 3.4356x over previous
//
#include <hip/hip_runtime.h>
#include <hip/hip_bf16.h>

typedef __attribute__((ext_vector_type(8))) short short8;
typedef __attribute__((ext_vector_type(4))) float f32x4;

#define MFMA16(A, B, C) __builtin_amdgcn_mfma_f32_16x16x32_bf16((A), (B), (C), 0, 0, 0)

#define GL16(gp, lp) __builtin_amdgcn_global_load_lds( \
    (const __attribute__((address_space(1))) void*)(gp), \
    (__attribute__((address_space(3))) void*)(lp), 16, 0, 0)

extern "C" __device__ float __ocml_native_exp2_f32(float);
#define EXP2(x) __ocml_native_exp2_f32(x)

__device__ __forceinline__ unsigned short bfbits(float f) {
  return __builtin_bit_cast(unsigned short, (__bf16)f);
}

constexpr int BH = 16;
constexpr int Mn = 2048;
constexpr int Dn = 64;
constexpr int LIMn = 2048;
constexpr size_t KF_SHORTS = (size_t)BH * 32 * 8 * 512;
constexpr size_t PE_JROWS = 132;
constexpr size_t PEF_SHORTS = PE_JROWS * 2 * 512;
constexpr int PART_SLOT = 4224;        // 64*64 o + 64 m + 64 l floats
constexpr int SLOTS_PER_HEAD = 72;     // sum of chunks for mt=8..31

__device__ __forceinline__ int part_offs(int mt) {
  return (mt < 16) ? 2 * (mt - 8) : (mt < 24 ? 16 + 3 * (mt - 16) : 40 + 4 * (mt - 24));
}

// ---------------- prep: fp32 -> bf16 MFMA-fragment-tiled layouts (verified r3-r11) ----------------

__global__ void prep_all(const float* __restrict__ K, const float* __restrict__ V,
                         const float* __restrict__ PE,
                         unsigned short* __restrict__ Kf, unsigned short* __restrict__ Vf,
                         unsigned short* __restrict__ PEf) {
  __shared__ float tA[64 * 64];
  __shared__ float tB[64 * 64];
  const int b = blockIdx.x, tid = threadIdx.x;
  const int w = tid >> 6, lane = tid & 63, g = lane >> 4, q15 = lane & 15;

  if (b < 512) {
    const int bh = b >> 5, lt = b & 31;
    const float* Ks = K + ((size_t)bh * Mn + lt * 64) * Dn;
    const float* Vs = V + ((size_t)bh * Mn + lt * 64) * Dn;
    const int row = tid >> 2, c0 = (tid & 3) * 16;
#pragma unroll
    for (int i = 0; i < 4; ++i) {
      *(float4*)&tA[row * 64 + c0 + 4 * i] = ((const float4*)(Ks + (size_t)row * 64 + c0))[i];
      *(float4*)&tB[row * 64 + c0 + 4 * i] = ((const float4*)(Vs + (size_t)row * 64 + c0))[i];
    }
    __syncthreads();
#pragma unroll
    for (int i = 0; i < 2; ++i) {
      const int f = 2 * w + i, nt = f >> 1, s = f & 1;
      short8 uk, uv;
#pragma unroll
      for (int jj = 0; jj < 8; ++jj) {
        uk[jj] = (short)bfbits(tA[(nt * 16 + q15) * 64 + s * 32 + g * 8 + jj]);
        uv[jj] = (short)bfbits(tB[(s * 32 + g * 8 + jj) * 64 + nt * 16 + q15]);
      }
      const size_t base = ((size_t)(bh * 32 + lt) * 8 + f) * 512 + lane * 8;
      *(short8*)&Kf[base] = uk;
      *(short8*)&Vf[base] = uv;
    }
  } else {
    const int pb = b - 512;
    const int c0 = pb * 64;
    const int d = tid >> 2, cc = (tid & 3) * 16;
#pragma unroll
    for (int i = 0; i < 16; ++i) {
      const int cx = c0 + cc + i;
      tA[(cc + i) * 64 + d] = (cx < LIMn) ? PE[(size_t)d * LIMn + cx] : 0.0f;
    }
    __syncthreads();
#pragma unroll
    for (int s = 0; s < 2; ++s) {
      short8 uu;
#pragma unroll
      for (int jj = 0; jj < 8; ++jj)
        uu[jj] = (short)bfbits(tA[(w * 16 + q15) * 64 + s * 32 + g * 8 + jj]);
      *(short8*)&PEf[((size_t)(4 * pb + w) * 2 + s) * 512 + lane * 8] = uu;
    }
  }
}

// ---------------- main: r9 structure + native exp2 + straight-line full-pair path ----------------

__launch_bounds__(256)
__global__ void stair_main(const float* __restrict__ Qg,
                           const unsigned short* __restrict__ Kf,
                           const unsigned short* __restrict__ Vf,
                           const unsigned short* __restrict__ PEf,
                           float* __restrict__ Og,
                           float* __restrict__ Part,
                           int split) {
  __shared__ __align__(16) unsigned short Kbuf[2][2][4096];  // [dbuf][tileslot][frags]
  __shared__ __align__(16) unsigned short Vbuf[2][2][4096];
  __shared__ __align__(16) unsigned short Plds[4][2048];     // per-wave, 2 tile slots

  const int tid = threadIdx.x;
  const int w = tid >> 6, lane = tid & 63, g = lane >> 4, q15 = lane & 15;
  const int bid = blockIdx.x;

  int bh, mt, chunk, t0, t1, nch;
  bh = bid & 15;                       // head -> fixed XCD: K/V/PE L2-resident
  if (split) {
    const int u = bid >> 4;            // 0..79, heavy-first
    if (u < 32)      { mt = 31 - (u >> 2); chunk = u & 3; }
    else if (u < 56) { const int v = u - 32, q = v / 3; mt = 23 - q; chunk = v - q * 3; }
    else if (u < 72) { const int v = u - 56; mt = 15 - (v >> 1); chunk = v & 1; }
    else             { mt = 7 - (u - 72); chunk = 0; }
    t0 = chunk * 8;
    t1 = (t0 + 8 < mt + 1) ? (t0 + 8) : (mt + 1);
    nch = (mt + 8) >> 3;
  } else {
    mt = 31 - (bid >> 4); chunk = 0; t0 = 0; t1 = mt + 1; nch = 1;
  }
  const int m0w = mt * 64 + w * 16;
  const int jb0 = 127 - 4 * mt - w;

  const float* Qb = Qg + (size_t)bh * Mn * Dn;
  float* Ob = Og + (size_t)bh * Mn * Dn;

  // Q A-fragments
  short8 aq[2];
  {
    const float* qp = Qb + (size_t)(m0w + q15) * Dn;
#pragma unroll
    for (int s = 0; s < 2; ++s) {
      const float4* p = (const float4*)(qp + s * 32 + g * 8);
      float4 f0 = p[0], f1 = p[1];
      short8 a;
      a[0]=(short)bfbits(f0.x); a[1]=(short)bfbits(f0.y); a[2]=(short)bfbits(f0.z); a[3]=(short)bfbits(f0.w);
      a[4]=(short)bfbits(f1.x); a[5]=(short)bfbits(f1.y); a[6]=(short)bfbits(f1.z); a[7]=(short)bfbits(f1.w);
      aq[s] = a;
    }
  }

  float mrun[4], lp[4];                 // lane-partial sums (verified r7-r9)
  f32x4 o[4] = {};
#pragma unroll
  for (int r = 0; r < 4; ++r) { mrun[r] = -1e30f; lp[r] = 0.0f; }

  auto STAGE1 = [&](int b, int slot, int t) {
    const size_t toff = ((size_t)(bh * 32 + t) * 8) * 512;
#pragma unroll
    for (int i = 0; i < 2; ++i) {
      const int f = 2 * w + i;
      const size_t off = toff + (size_t)f * 512 + lane * 8;
      GL16(&Kf[off], &Kbuf[b][slot][f * 512]);
      GL16(&Vf[off], &Vbuf[b][slot][f * 512]);
    }
  };

  auto PV = [&](const float sv[4][4], int cur, int slot, int smax) {
#pragma unroll
    for (int nt = 0; nt < 4; ++nt)
#pragma unroll
      for (int r = 0; r < 4; ++r) {
        const int rw = g * 4 + r;
        Plds[w][slot * 1024 + ((rw * 64 + nt * 16 + q15) ^ ((rw & 7) << 3))] = bfbits(sv[nt][r]);
      }
    short8 pa[2];
#pragma unroll
    for (int s = 0; s < 2; ++s)
      if (s <= smax)
        pa[s] = *(short8*)&Plds[w][slot * 1024 + ((q15 * 64 + s * 32 + g * 8) ^ ((q15 & 7) << 3))];
#pragma unroll
    for (int s = 0; s < 2; ++s)
      if (s <= smax)
#pragma unroll
        for (int nt = 0; nt < 4; ++nt) {
          short8 bfr = *(const short8*)&Vbuf[cur][slot][(nt * 2 + s) * 512 + lane * 8];
          o[nt] = MFMA16(pa[s], bfr, o[nt]);
        }
  };

  // shared softmax tail over a full pair of sv blocks (lane-partial sums)
  auto SOFTMAX2 = [&](float svA[4][4], float svB[4][4]) {
    float lmax[4];
#pragma unroll
    for (int r = 0; r < 4; ++r) {
      float a = fmaxf(fmaxf(svA[0][r], svA[1][r]), fmaxf(svA[2][r], svA[3][r]));
      float b = fmaxf(fmaxf(svB[0][r], svB[1][r]), fmaxf(svB[2][r], svB[3][r]));
      lmax[r] = fmaxf(a, b);
    }
    const bool fast = __all((lmax[0] <= mrun[0] + 8.f) & (lmax[1] <= mrun[1] + 8.f) &
                            (lmax[2] <= mrun[2] + 8.f) & (lmax[3] <= mrun[3] + 8.f));
    if (!fast) {
#pragma unroll
      for (int r = 0; r < 4; ++r) {
        float mx = lmax[r];
        mx = fmaxf(mx, __shfl_xor(mx, 1));
        mx = fmaxf(mx, __shfl_xor(mx, 2));
        mx = fmaxf(mx, __shfl_xor(mx, 4));
        mx = fmaxf(mx, __shfl_xor(mx, 8));
        const float mn = fmaxf(mrun[r], mx);
        const float alpha = EXP2((mrun[r] - mn) * 1.44269504f);
        mrun[r] = mn;
        lp[r] *= alpha;
        o[0][r] *= alpha; o[1][r] *= alpha; o[2][r] *= alpha; o[3][r] *= alpha;
      }
    }
#pragma unroll
    for (int nt = 0; nt < 4; ++nt)
#pragma unroll
      for (int r = 0; r < 4; ++r) {
        svA[nt][r] = EXP2((svA[nt][r] - mrun[r]) * 1.44269504f);
        svB[nt][r] = EXP2((svB[nt][r] - mrun[r]) * 1.44269504f);
      }
#pragma unroll
    for (int r = 0; r < 4; ++r)
      lp[r] += ((svA[0][r] + svA[1][r]) + (svA[2][r] + svA[3][r])) +
               ((svB[0][r] + svB[1][r]) + (svB[2][r] + svB[3][r]));
  };

  // ---- PAIRF: straight-line full pair (no diag, no guards) — the hot path ----
  auto PAIRF = [&](int t, int cur) {
    const int jbA = jb0 + 4 * t;
    const int jbB = jbA + 4;

    short8 peA[2][5], peB[2][5];
#pragma unroll
    for (int s = 0; s < 2; ++s)
#pragma unroll
      for (int uu = 0; uu < 5; ++uu) {
        peA[s][uu] = *(const short8*)&PEf[((size_t)(jbA + uu) * 2 + s) * 512 + lane * 8];
        peB[s][uu] = *(const short8*)&PEf[((size_t)(jbB + uu) * 2 + s) * 512 + lane * 8];
      }

    f32x4 qkA[4] = {}, qkB[4] = {};
#pragma unroll
    for (int s = 0; s < 2; ++s)
#pragma unroll
      for (int nt = 0; nt < 4; ++nt) {
        short8 ba = *(const short8*)&Kbuf[cur][0][(nt * 2 + s) * 512 + lane * 8];
        qkA[nt] = MFMA16(aq[s], ba, qkA[nt]);
        short8 bb = *(const short8*)&Kbuf[cur][1][(nt * 2 + s) * 512 + lane * 8];
        qkB[nt] = MFMA16(aq[s], bb, qkB[nt]);
      }

    f32x4 evA[5] = {};
#pragma unroll
    for (int s = 0; s < 2; ++s)
#pragma unroll
      for (int uu = 0; uu < 5; ++uu) evA[uu] = MFMA16(aq[s], peA[s][uu], evA[uu]);

    float svA[4][4], svB[4][4];
    // gather A (single-shuffle; full, unmasked)
#pragma unroll
    for (int nt = 0; nt < 4; ++nt)
#pragma unroll
      for (int r = 0; r < 4; ++r) {
        const int rw = g * 4 + r;
        const int srcLane = (lane & 48) | ((q15 + 15 - rw) & 15);
        const bool cond = (((q15 + rw + 1) & 15) > rw);
        const float sel = cond ? evA[nt + 1][r] : evA[nt][r];
        svA[nt][r] = (qkA[nt][r] + __shfl(sel, srcLane, 64)) * 0.125f;
      }

    f32x4 evB[5] = {};
#pragma unroll
    for (int s = 0; s < 2; ++s)
#pragma unroll
      for (int uu = 0; uu < 5; ++uu) evB[uu] = MFMA16(aq[s], peB[s][uu], evB[uu]);

#pragma unroll
    for (int nt = 0; nt < 4; ++nt)
#pragma unroll
      for (int r = 0; r < 4; ++r) {
        const int rw = g * 4 + r;
        const int srcLane = (lane & 48) | ((q15 + 15 - rw) & 15);
        const bool cond = (((q15 + rw + 1) & 15) > rw);
        const float sel = cond ? evB[nt + 1][r] : evB[nt][r];
        svB[nt][r] = (qkB[nt][r] + __shfl(sel, srcLane, 64)) * 0.125f;
      }

    SOFTMAX2(svA, svB);
    PV(svA, cur, 0, 1);
    PV(svB, cur, 1, 1);
  };

  // ---- PAIRD: last pair of the diag chunk (B-tile is diagonal) ----
  auto PAIRD = [&](int t, int cur) {
    const int jbA = jb0 + 4 * t;
    const int jbB = jbA + 4;
    const int ntmaxB = w;
    const int u5B = w + 2;
    const int smaxB = w >> 1;

    short8 peA[2][5], peB[2][5];
#pragma unroll
    for (int s = 0; s < 2; ++s)
#pragma unroll
      for (int uu = 0; uu < 5; ++uu) {
        peA[s][uu] = *(const short8*)&PEf[((size_t)(jbA + uu) * 2 + s) * 512 + lane * 8];
        if (uu < u5B)
          peB[s][uu] = *(const short8*)&PEf[((size_t)(jbB + uu) * 2 + s) * 512 + lane * 8];
      }

    f32x4 qkA[4] = {}, qkB[4] = {};
#pragma unroll
    for (int s = 0; s < 2; ++s)
#pragma unroll
      for (int nt = 0; nt < 4; ++nt) {
        short8 ba = *(const short8*)&Kbuf[cur][0][(nt * 2 + s) * 512 + lane * 8];
        qkA[nt] = MFMA16(aq[s], ba, qkA[nt]);
        if (nt <= ntmaxB) {
          short8 bb = *(const short8*)&Kbuf[cur][1][(nt * 2 + s) * 512 + lane * 8];
          qkB[nt] = MFMA16(aq[s], bb, qkB[nt]);
        }
      }

    f32x4 evA[5] = {};
#pragma unroll
    for (int s = 0; s < 2; ++s)
#pragma unroll
      for (int uu = 0; uu < 5; ++uu) evA[uu] = MFMA16(aq[s], peA[s][uu], evA[uu]);

    float svA[4][4], svB[4][4];
#pragma unroll
    for (int nt = 0; nt < 4; ++nt)
#pragma unroll
      for (int r = 0; r < 4; ++r) {
        const int rw = g * 4 + r;
        const int srcLane = (lane & 48) | ((q15 + 15 - rw) & 15);
        const bool cond = (((q15 + rw + 1) & 15) > rw);
        const float sel = cond ? evA[nt + 1][r] : evA[nt][r];
        svA[nt][r] = (qkA[nt][r] + __shfl(sel, srcLane, 64)) * 0.125f;
        svB[nt][r] = -1e30f;
      }

    f32x4 evB[5] = {};
#pragma unroll
    for (int s = 0; s < 2; ++s)
#pragma unroll
      for (int uu = 0; uu < 5; ++uu)
        if (uu < u5B) evB[uu] = MFMA16(aq[s], peB[s][uu], evB[uu]);

#pragma unroll
    for (int nt = 0; nt < 4; ++nt)
      if (nt <= ntmaxB) {
#pragma unroll
        for (int r = 0; r < 4; ++r) {
          const int rw = g * 4 + r;
          const int srcLane = (lane & 48) | ((q15 + 15 - rw) & 15);
          const bool cond = (((q15 + rw + 1) & 15) > rw);
          const float sel = cond ? evB[nt + 1][r] : evB[nt][r];
          const float er = __shfl(sel, srcLane, 64);
          const int li = nt * 16 + q15;
          const bool masked = (li > w * 16 + rw);
          svB[nt][r] = masked ? -1e30f : (qkB[nt][r] + er) * 0.125f;
        }
      }

    SOFTMAX2(svA, svB);
    PV(svA, cur, 0, 1);
    PV(svB, cur, 1, smaxB);
  };

  // ---- SINGLE: odd-remainder tile (may be diagonal) ----
  auto SINGLE = [&](int t, int cur, bool diag) {
    const int jb = jb0 + 4 * t;
    const int ntmax = diag ? w : 3;
    const int u5 = diag ? (w + 2) : 5;
    const int smax = diag ? (w >> 1) : 1;

    short8 pe[2][5];
#pragma unroll
    for (int s = 0; s < 2; ++s)
#pragma unroll
      for (int uu = 0; uu < 5; ++uu)
        if (uu < u5)
          pe[s][uu] = *(const short8*)&PEf[((size_t)(jb + uu) * 2 + s) * 512 + lane * 8];

    f32x4 qk[4] = {};
#pragma unroll
    for (int s = 0; s < 2; ++s)
#pragma unroll
      for (int nt = 0; nt < 4; ++nt)
        if (nt <= ntmax) {
          short8 bfr = *(const short8*)&Kbuf[cur][0][(nt * 2 + s) * 512 + lane * 8];
          qk[nt] = MFMA16(aq[s], bfr, qk[nt]);
        }
    f32x4 ev[5] = {};
#pragma unroll
    for (int s = 0; s < 2; ++s)
#pragma unroll
      for (int uu = 0; uu < 5; ++uu)
        if (uu < u5) ev[uu] = MFMA16(aq[s], pe[s][uu], ev[uu]);

    float sv[4][4];
#pragma unroll
    for (int nt = 0; nt < 4; ++nt)
#pragma unroll
      for (int r = 0; r < 4; ++r) sv[nt][r] = -1e30f;
#pragma unroll
    for (int nt = 0; nt < 4; ++nt)
      if (nt <= ntmax) {
#pragma unroll
        for (int r = 0; r < 4; ++r) {
          const int rw = g * 4 + r;
          const int srcLane = (lane & 48) | ((q15 + 15 - rw) & 15);
          const bool cond = (((q15 + rw + 1) & 15) > rw);
          const float sel = cond ? ev[nt + 1][r] : ev[nt][r];
          const float er = __shfl(sel, srcLane, 64);
          const int li = nt * 16 + q15;
          const bool masked = diag && (li > w * 16 + rw);
          sv[nt][r] = masked ? -1e30f : (qk[nt][r] + er) * 0.125f;
        }
      }

    float lmax[4];
#pragma unroll
    for (int r = 0; r < 4; ++r)
      lmax[r] = fmaxf(fmaxf(sv[0][r], sv[1][r]), fmaxf(sv[2][r], sv[3][r]));
    const bool fast = __all((lmax[0] <= mrun[0] + 8.f) & (lmax[1] <= mrun[1] + 8.f) &
                            (lmax[2] <= mrun[2] + 8.f) & (lmax[3] <= mrun[3] + 8.f));
    if (!fast) {
#pragma unroll
      for (int r = 0; r < 4; ++r) {
        float mx = lmax[r];
        mx = fmaxf(mx, __shfl_xor(mx, 1));
        mx = fmaxf(mx, __shfl_xor(mx, 2));
        mx = fmaxf(mx, __shfl_xor(mx, 4));
        mx = fmaxf(mx, __shfl_xor(mx, 8));
        const float mn = fmaxf(mrun[r], mx);
        const float alpha = EXP2((mrun[r] - mn) * 1.44269504f);
        mrun[r] = mn;
        lp[r] *= alpha;
        o[0][r] *= alpha; o[1][r] *= alpha; o[2][r] *= alpha; o[3][r] *= alpha;
      }
    }
#pragma unroll
    for (int nt = 0; nt < 4; ++nt)
#pragma unroll
      for (int r = 0; r < 4; ++r)
        sv[nt][r] = EXP2((sv[nt][r] - mrun[r]) * 1.44269504f);
#pragma unroll
    for (int r = 0; r < 4; ++r)
      lp[r] += (sv[0][r] + sv[1][r]) + (sv[2][r] + sv[3][r]);
    PV(sv, cur, 0, smax);
  };

  // ---- main loop over pairs (dbuf K/V staging, one barrier per pair) ----
  {
    int cur = 0;
    int t = t0;
    const int n0 = (t1 - t0 >= 2) ? 2 : 1;
    STAGE1(0, 0, t0);
    if (n0 == 2) STAGE1(0, 1, t0 + 1);
    __syncthreads();
    while (t < t1) {
      const int n = (t1 - t >= 2) ? 2 : 1;
      const int rem = t1 - (t + n);
      const int nn = (rem >= 2) ? 2 : rem;
      if (nn > 0) {
        STAGE1(cur ^ 1, 0, t + n);
        if (nn == 2) STAGE1(cur ^ 1, 1, t + n + 1);
      }
      if (n == 2) {
        if (t + 1 == mt) PAIRD(t, cur);
        else PAIRF(t, cur);
      } else {
        SINGLE(t, cur, (t == mt));
      }
      if (nn > 0) __syncthreads();
      cur ^= 1;
      t += n;
    }
  }

  // ---- epilogue: one-time butterfly of lane-partial sums ----
  float lr[4];
#pragma unroll
  for (int r = 0; r < 4; ++r) {
    float s = lp[r];
    s += __shfl_xor(s, 1);
    s += __shfl_xor(s, 2);
    s += __shfl_xor(s, 4);
    s += __shfl_xor(s, 8);
    lr[r] = s;
  }

  if (nch == 1) {
#pragma unroll
    for (int nt = 0; nt < 4; ++nt)
#pragma unroll
      for (int r = 0; r < 4; ++r) {
        const int m = m0w + g * 4 + r;
        Ob[(size_t)m * Dn + nt * 16 + q15] = o[nt][r] / lr[r];
      }
  } else {
    float* ps = Part + ((size_t)bh * SLOTS_PER_HEAD + part_offs(mt) + chunk) * PART_SLOT;
#pragma unroll
    for (int nt = 0; nt < 4; ++nt)
#pragma unroll
      for (int r = 0; r < 4; ++r)
        ps[(w * 16 + g * 4 + r) * 64 + nt * 16 + q15] = o[nt][r];
#pragma unroll
    for (int r = 0; r < 4; ++r)
      if (q15 == g * 4 + r) {
        ps[4096 + w * 16 + q15] = mrun[r];
        ps[4160 + w * 16 + q15] = lr[r];
      }
  }
}

// ---------------- combine: merge 2-4 chunk partials per (head, mtile>=8) ----------------

__launch_bounds__(256, 4)
__global__ void combine_parts(const float* __restrict__ Part, float* __restrict__ Og) {
  const int bid = blockIdx.x;
  const int bh = bid & 15;
  const int mt = 8 + (bid >> 4);
  const int nch = (mt + 8) >> 3;
  const float* base = Part + ((size_t)bh * SLOTS_PER_HEAD + part_offs(mt)) * PART_SLOT;
  const int tid = threadIdx.x;
  const int row = tid >> 2;
  const int qc = (tid & 3) * 16;

  float mstar = -1e30f;
#pragma unroll
  for (int cc = 0; cc < 4; ++cc)
    if (cc < nch) mstar = fmaxf(mstar, base[cc * PART_SLOT + 4096 + row]);
  float lsum = 0.f;
  f32x4 acc0 = {}, acc1 = {}, acc2 = {}, acc3 = {};
#pragma unroll
  for (int cc = 0; cc < 4; ++cc)
    if (cc < nch) {
      const float* ps = base + cc * PART_SLOT;
      const float sc = EXP2((ps[4096 + row] - mstar) * 1.44269504f);
      lsum += ps[4160 + row] * sc;
      const f32x4* op = (const f32x4*)&ps[row * 64 + qc];
      acc0 += op[0] * sc; acc1 += op[1] * sc; acc2 += op[2] * sc; acc3 += op[3] * sc;
    }
  const float inv = 1.f / lsum;
  float* dst = Og + ((size_t)bh * Mn + mt * 64 + row) * Dn + qc;
  *(f32x4*)&dst[0]  = acc0 * inv;
  *(f32x4*)&dst[4]  = acc1 * inv;
  *(f32x4*)&dst[8]  = acc2 * inv;
  *(f32x4*)&dst[12] = acc3 * inv;
}

// ---------------- fallback (round-1 kernel, passed @118us, no ws needed) ----------------

constexpr int ESTRIDE = 84;

__launch_bounds__(256, 2)
__global__ void stair_attn_fb(const float* __restrict__ Qg,
                              const float* __restrict__ Kg,
                              const float* __restrict__ Vg,
                              const float* __restrict__ PEg,
                              float* __restrict__ Og) {
  __shared__ __align__(16) unsigned short Kb[64 * 64];
  __shared__ __align__(16) unsigned short Vt[64 * 64];
  __shared__ __align__(16) unsigned short Pb[128 * 64];
  __shared__ __align__(16) float Elds[4 * 16 * ESTRIDE];
  __shared__ __align__(16) unsigned short Plds[4 * 16 * 64];

  const int tid = threadIdx.x;
  const int w = tid >> 6;
  const int lane = tid & 63;
  const int g = lane >> 4;
  const int q15 = lane & 15;

  const int bid = blockIdx.x;
  const int bh = bid & 15;
  const int jid = bid >> 4;
  const int mt = (jid < 16) ? (2 * jid) : (63 - 2 * jid);
  const int m0 = mt * 64;

  const float* Qb = Qg + (size_t)bh * Mn * Dn;
  const float* Kbase = Kg + (size_t)bh * Mn * Dn;
  const float* Vbase = Vg + (size_t)bh * Mn * Dn;
  float* Ob = Og + (size_t)bh * Mn * Dn;

  short8 aq[2];
  {
    const float* qp = Qb + (size_t)(m0 + 16 * w + q15) * Dn;
#pragma unroll
    for (int s = 0; s < 2; ++s) {
      const float4* p = (const float4*)(qp + s * 32 + g * 8);
      float4 f0 = p[0], f1 = p[1];
      short8 a;
      a[0]=(short)bfbits(f0.x); a[1]=(short)bfbits(f0.y); a[2]=(short)bfbits(f0.z); a[3]=(short)bfbits(f0.w);
      a[4]=(short)bfbits(f1.x); a[5]=(short)bfbits(f1.y); a[6]=(short)bfbits(f1.z); a[7]=(short)bfbits(f1.w);
      aq[s] = a;
    }
  }

  float mrun[4], lrun[4];
  f32x4 o[4] = {};
#pragma unroll
  for (int r = 0; r < 4; ++r) { mrun[r] = -1e30f; lrun[r] = 0.0f; }

  const int ntiles = mt + 1;
  const int dso = g * 8;

  for (int t = 0; t < ntiles; ++t) {
    const int l0 = t * 64;
    __syncthreads();
    {
      const int l = tid >> 2;
      const int dq = (tid & 3) * 16;
      const float* kp = Kbase + (size_t)(l0 + l) * Dn + dq;
      short8 u0, u1;
      {
        float4 f = ((const float4*)kp)[0];
        u0[0]=(short)bfbits(f.x); u0[1]=(short)bfbits(f.y); u0[2]=(short)bfbits(f.z); u0[3]=(short)bfbits(f.w);
        f = ((const float4*)kp)[1];
        u0[4]=(short)bfbits(f.x); u0[5]=(short)bfbits(f.y); u0[6]=(short)bfbits(f.z); u0[7]=(short)bfbits(f.w);
        f = ((const float4*)kp)[2];
        u1[0]=(short)bfbits(f.x); u1[1]=(short)bfbits(f.y); u1[2]=(short)bfbits(f.z); u1[3]=(short)bfbits(f.w);
        f = ((const float4*)kp)[3];
        u1[4]=(short)bfbits(f.x); u1[5]=(short)bfbits(f.y); u1[6]=(short)bfbits(f.z); u1[7]=(short)bfbits(f.w);
      }
      const int swz = (l & 7) << 3;
      *(short8*)&Kb[(l * 64 + dq) ^ swz] = u0;
      *(short8*)&Kb[(l * 64 + dq + 8) ^ swz] = u1;
    }
    {
      const int lrow = lane;
      const int ds = w * 16;
      const float* vp = Vbase + (size_t)(l0 + lrow) * Dn + ds;
#pragma unroll
      for (int i = 0; i < 4; ++i) {
        float4 f = ((const float4*)vp)[i];
        int c0 = ds + 4 * i;
        Vt[((c0 + 0) * 64 + lrow) ^ (((c0 + 0) & 7) << 3)] = bfbits(f.x);
        Vt[((c0 + 1) * 64 + lrow) ^ (((c0 + 1) & 7) << 3)] = bfbits(f.y);
        Vt[((c0 + 2) * 64 + lrow) ^ (((c0 + 2) & 7) << 3)] = bfbits(f.z);
        Vt[((c0 + 3) * 64 + lrow) ^ (((c0 + 3) & 7) << 3)] = bfbits(f.w);
      }
    }
    {
      const int d = lane;
      const int cc = w * 32;
      const int cb = (2048 - 64) - m0 + l0;
      const float* pp = PEg + (size_t)d * LIMn + (cb + cc);
      if (cb + cc + 31 < LIMn) {
#pragma unroll
        for (int i = 0; i < 8; ++i) {
          float4 f = ((const float4*)pp)[i];
          int c0 = cc + 4 * i;
          Pb[((c0 + 0) * 64 + d) ^ (((c0 + 0) & 7) << 3)] = bfbits(f.x);
          Pb[((c0 + 1) * 64 + d) ^ (((c0 + 1) & 7) << 3)] = bfbits(f.y);
          Pb[((c0 + 2) * 64 + d) ^ (((c0 + 2) & 7) << 3)] = bfbits(f.z);
          Pb[((c0 + 3) * 64 + d) ^ (((c0 + 3) & 7) << 3)] = bfbits(f.w);
        }
      } else {
        for (int i = 0; i < 32; ++i) {
          int cabs = cb + cc + i;
          float f = (cabs < LIMn) ? pp[i] : 0.0f;
          int c0 = cc + i;
          Pb[(c0 * 64 + d) ^ ((c0 & 7) << 3)] = bfbits(f);
        }
      }
    }
    __syncthreads();

    f32x4 qk[4] = {};
#pragma unroll
    for (int s = 0; s < 2; ++s)
#pragma unroll
      for (int nt = 0; nt < 4; ++nt) {
        int l = nt * 16 + q15;
        short8 b = *(short8*)&Kb[(l * 64 + s * 32 + dso) ^ ((l & 7) << 3)];
        qk[nt] = MFMA16(aq[s], b, qk[nt]);
      }

    f32x4 ev[5] = {};
    const int ntb = 3 - w;
#pragma unroll
    for (int s = 0; s < 2; ++s)
#pragma unroll
      for (int u5 = 0; u5 < 5; ++u5) {
        int c = (ntb + u5) * 16 + q15;
        short8 b = *(short8*)&Pb[(c * 64 + s * 32 + dso) ^ ((c & 7) << 3)];
        ev[u5] = MFMA16(aq[s], b, ev[u5]);
      }
    float* Ew = Elds + w * 16 * ESTRIDE;
#pragma unroll
    for (int u5 = 0; u5 < 5; ++u5)
#pragma unroll
      for (int r = 0; r < 4; ++r)
        Ew[(g * 4 + r) * ESTRIDE + u5 * 16 + q15] = ev[u5][r];

    const bool diag = (t == ntiles - 1);
    float sv[4][4];
#pragma unroll
    for (int nt = 0; nt < 4; ++nt) {
      int li = nt * 16 + q15;
#pragma unroll
      for (int r = 0; r < 4; ++r) {
        int rw = g * 4 + r;
        float eread = Ew[rw * ESTRIDE + (15 - rw + li)];
        bool masked = diag && (li > (16 * w + rw));
        sv[nt][r] = masked ? -1e30f : (qk[nt][r] + eread) * 0.125f;
      }
    }

    float mnew[4], alpha[4];
#pragma unroll
    for (int r = 0; r < 4; ++r) {
      float mx = fmaxf(fmaxf(sv[0][r], sv[1][r]), fmaxf(sv[2][r], sv[3][r]));
      mx = fmaxf(mx, __shfl_xor(mx, 1));
      mx = fmaxf(mx, __shfl_xor(mx, 2));
      mx = fmaxf(mx, __shfl_xor(mx, 4));
      mx = fmaxf(mx, __shfl_xor(mx, 8));
      float mn = fmaxf(mrun[r], mx);
      alpha[r] = exp2f((mrun[r] - mn) * 1.44269504f);
      mnew[r] = mn;
      mrun[r] = mn;
    }
    float pexp[4][4];
#pragma unroll
    for (int nt = 0; nt < 4; ++nt)
#pragma unroll
      for (int r = 0; r < 4; ++r)
        pexp[nt][r] = exp2f((sv[nt][r] - mnew[r]) * 1.44269504f);
#pragma unroll
    for (int r = 0; r < 4; ++r) {
      float sum = (pexp[0][r] + pexp[1][r]) + (pexp[2][r] + pexp[3][r]);
      sum += __shfl_xor(sum, 1);
      sum += __shfl_xor(sum, 2);
      sum += __shfl_xor(sum, 4);
      sum += __shfl_xor(sum, 8);
      lrun[r] = lrun[r] * alpha[r] + sum;
      o[0][r] *= alpha[r];
      o[1][r] *= alpha[r];
      o[2][r] *= alpha[r];
      o[3][r] *= alpha[r];
    }

    unsigned short* Pw = Plds + w * 16 * 64;
#pragma unroll
    for (int nt = 0; nt < 4; ++nt)
#pragma unroll
      for (int r = 0; r < 4; ++r) {
        int rw = g * 4 + r;
        Pw[(rw * 64 + nt * 16 + q15) ^ ((rw & 7) << 3)] = bfbits(pexp[nt][r]);
      }
    short8 pa[2];
#pragma unroll
    for (int s = 0; s < 2; ++s)
      pa[s] = *(short8*)&Pw[(q15 * 64 + s * 32 + dso) ^ ((q15 & 7) << 3)];

#pragma unroll
    for (int s = 0; s < 2; ++s)
#pragma unroll
      for (int nt = 0; nt < 4; ++nt) {
        int d = nt * 16 + q15;
        short8 b = *(short8*)&Vt[(d * 64 + s * 32 + dso) ^ ((d & 7) << 3)];
        o[nt] = MFMA16(pa[s], b, o[nt]);
      }
  }

#pragma unroll
  for (int nt = 0; nt < 4; ++nt)
#pragma unroll
    for (int r = 0; r < 4; ++r) {
      int m = m0 + 16 * w + g * 4 + r;
      Ob[(size_t)m * Dn + nt * 16 + q15] = o[nt][r] / lrun[r];
    }
}

// ---------------- launch ----------------

extern "C" void kernel_launch(void* const* d_in, const int* in_sizes, int n_in,
                              void* d_out, int out_size, void* d_ws, size_t ws_size,
                              hipStream_t stream) {
  (void)in_sizes; (void)n_in; (void)out_size;
  const float* Q  = (const float*)d_in[0];
  const float* K  = (const float*)d_in[1];
  const float* V  = (const float*)d_in[2];
  const float* PE = (const float*)d_in[3];
  float* Out = (float*)d_out;

  const size_t szK = KF_SHORTS * sizeof(unsigned short);              // 4 MB
  const size_t szV = szK;                                              // 4 MB
  const size_t szP = PEF_SHORTS * sizeof(unsigned short);              // 264 KB
  const size_t szPart = (size_t)BH * SLOTS_PER_HEAD * PART_SLOT * 4;   // 19.5 MB
  const size_t need1 = szK + szV + szP;
  const size_t need2 = need1 + szPart;

  if (ws_size >= need1) {
    unsigned short* Kf  = (unsigned short*)d_ws;
    unsigned short* Vf  = (unsigned short*)((char*)d_ws + szK);
    unsigned short* PEf = (unsigned short*)((char*)d_ws + szK + szV);
    float* Part = (float*)((char*)d_ws + need1);

    hipLaunchKernelGGL(prep_all, dim3(512 + 33), dim3(256), 0, stream, K, V, PE, Kf, Vf, PEf);
    if (ws_size >= need2) {
      hipLaunchKernelGGL(stair_main, dim3(BH * 80), dim3(256), 0, stream,
                         Q, Kf, Vf, PEf, Out, Part, 1);
      hipLaunchKernelGGL(combine_parts, dim3(BH * 24), dim3(256), 0, stream, Part, Out);
    } else {
      hipLaunchKernelGGL(stair_main, dim3(512), dim3(256), 0, stream,
                         Q, Kf, Vf, PEf, Out, (float*)d_ws, 0);
    }
  } else {
    hipLaunchKernelGGL(stair_attn_fb, dim3(512), dim3(256), 0, stream, Q, K, V, PE, Out);
  }
}

// Round 13
// 65.426 us; speedup vs baseline: 3.5116x; 1.0221x over previous
//
#include <hip/hip_runtime.h>
#include <hip/hip_bf16.h>

typedef __attribute__((ext_vector_type(8))) short short8;
typedef __attribute__((ext_vector_type(4))) float f32x4;

#define MFMA16(A, B, C) __builtin_amdgcn_mfma_f32_16x16x32_bf16((A), (B), (C), 0, 0, 0)

#define GL16(gp, lp) __builtin_amdgcn_global_load_lds( \
    (const __attribute__((address_space(1))) void*)(gp), \
    (__attribute__((address_space(3))) void*)(lp), 16, 0, 0)

extern "C" __device__ float __ocml_native_exp2_f32(float);
#define EXP2(x) __ocml_native_exp2_f32(x)

__device__ __forceinline__ unsigned short bfbits(float f) {
  return __builtin_bit_cast(unsigned short, (__bf16)f);
}

constexpr int BH = 16;
constexpr int Mn = 2048;
constexpr int Dn = 64;
constexpr int LIMn = 2048;
constexpr size_t KF_SHORTS = (size_t)BH * 32 * 8 * 512;
constexpr size_t PE_JROWS = 132;
constexpr size_t PEF_SHORTS = PE_JROWS * 2 * 512;
constexpr int PART_SLOT = 4224;        // 64*64 o + 64 m + 64 l floats
constexpr int SLOTS_PER_HEAD = 72;     // sum of chunks for mt=8..31
constexpr float QSCALE = 0.125f * 1.44269504f;   // fold 1/sqrt(64) and log2(e) into Q
constexpr float THR = 11.5409504f;               // 8 * log2(e), defer-max in exp2 domain

__device__ __forceinline__ int part_offs(int mt) {
  return (mt < 16) ? 2 * (mt - 8) : (mt < 24 ? 16 + 3 * (mt - 16) : 40 + 4 * (mt - 24));
}

// ---------------- prep: fp32 -> bf16 MFMA-fragment-tiled layouts (verified r3-r12) ----------------

__global__ void prep_all(const float* __restrict__ K, const float* __restrict__ V,
                         const float* __restrict__ PE,
                         unsigned short* __restrict__ Kf, unsigned short* __restrict__ Vf,
                         unsigned short* __restrict__ PEf) {
  __shared__ float tA[64 * 64];
  __shared__ float tB[64 * 64];
  const int b = blockIdx.x, tid = threadIdx.x;
  const int w = tid >> 6, lane = tid & 63, g = lane >> 4, q15 = lane & 15;

  if (b < 512) {
    const int bh = b >> 5, lt = b & 31;
    const float* Ks = K + ((size_t)bh * Mn + lt * 64) * Dn;
    const float* Vs = V + ((size_t)bh * Mn + lt * 64) * Dn;
    const int row = tid >> 2, c0 = (tid & 3) * 16;
#pragma unroll
    for (int i = 0; i < 4; ++i) {
      *(float4*)&tA[row * 64 + c0 + 4 * i] = ((const float4*)(Ks + (size_t)row * 64 + c0))[i];
      *(float4*)&tB[row * 64 + c0 + 4 * i] = ((const float4*)(Vs + (size_t)row * 64 + c0))[i];
    }
    __syncthreads();
#pragma unroll
    for (int i = 0; i < 2; ++i) {
      const int f = 2 * w + i, nt = f >> 1, s = f & 1;
      short8 uk, uv;
#pragma unroll
      for (int jj = 0; jj < 8; ++jj) {
        uk[jj] = (short)bfbits(tA[(nt * 16 + q15) * 64 + s * 32 + g * 8 + jj]);
        uv[jj] = (short)bfbits(tB[(s * 32 + g * 8 + jj) * 64 + nt * 16 + q15]);
      }
      const size_t base = ((size_t)(bh * 32 + lt) * 8 + f) * 512 + lane * 8;
      *(short8*)&Kf[base] = uk;
      *(short8*)&Vf[base] = uv;
    }
  } else {
    const int pb = b - 512;
    const int c0 = pb * 64;
    const int d = tid >> 2, cc = (tid & 3) * 16;
#pragma unroll
    for (int i = 0; i < 16; ++i) {
      const int cx = c0 + cc + i;
      tA[(cc + i) * 64 + d] = (cx < LIMn) ? PE[(size_t)d * LIMn + cx] : 0.0f;
    }
    __syncthreads();
#pragma unroll
    for (int s = 0; s < 2; ++s) {
      short8 uu;
#pragma unroll
      for (int jj = 0; jj < 8; ++jj)
        uu[jj] = (short)bfbits(tA[(w * 16 + q15) * 64 + s * 32 + g * 8 + jj]);
      *(short8*)&PEf[((size_t)(4 * pb + w) * 2 + s) * 512 + lane * 8] = uu;
    }
  }
}

// ---------------- main: 53KB LDS (3 blocks/CU), V single-buffer, exp2-domain ----------------

__launch_bounds__(256)
__global__ void stair_main(const float* __restrict__ Qg,
                           const unsigned short* __restrict__ Kf,
                           const unsigned short* __restrict__ Vf,
                           const unsigned short* __restrict__ PEf,
                           float* __restrict__ Og,
                           float* __restrict__ Part,
                           int split) {
  __shared__ __align__(16) unsigned short Kbuf[2][2][4096];  // dbuf K pair: 32KB
  __shared__ __align__(16) unsigned short Vbuf[2][4096];     // single-buffered V pair: 16KB
  __shared__ __align__(16) unsigned short Plds[4][640];      // per-wave 16x40-short bounce: 5KB

  const int tid = threadIdx.x;
  const int w = tid >> 6, lane = tid & 63, g = lane >> 4, q15 = lane & 15;
  const int bid = blockIdx.x;

  int bh, mt, chunk, t0, t1, nch;
  bh = bid & 15;                       // head -> fixed XCD: K/V/PE L2-resident
  if (split) {
    const int u = bid >> 4;            // 0..79, heavy-first
    if (u < 32)      { mt = 31 - (u >> 2); chunk = u & 3; }
    else if (u < 56) { const int v = u - 32, q = v / 3; mt = 23 - q; chunk = v - q * 3; }
    else if (u < 72) { const int v = u - 56; mt = 15 - (v >> 1); chunk = v & 1; }
    else             { mt = 7 - (u - 72); chunk = 0; }
    t0 = chunk * 8;
    t1 = (t0 + 8 < mt + 1) ? (t0 + 8) : (mt + 1);
    nch = (mt + 8) >> 3;
  } else {
    mt = 31 - (bid >> 4); chunk = 0; t0 = 0; t1 = mt + 1; nch = 1;
  }
  const int m0w = mt * 64 + w * 16;
  const int jb0 = 127 - 4 * mt - w;

  const float* Qb = Qg + (size_t)bh * Mn * Dn;
  float* Ob = Og + (size_t)bh * Mn * Dn;
  unsigned short* Pw = Plds[w];

  // Q A-fragments, pre-scaled by 0.125*log2(e) (exp2-domain scores)
  short8 aq[2];
  {
    const float* qp = Qb + (size_t)(m0w + q15) * Dn;
#pragma unroll
    for (int s = 0; s < 2; ++s) {
      const float4* p = (const float4*)(qp + s * 32 + g * 8);
      float4 f0 = p[0], f1 = p[1];
      short8 a;
      a[0]=(short)bfbits(f0.x*QSCALE); a[1]=(short)bfbits(f0.y*QSCALE);
      a[2]=(short)bfbits(f0.z*QSCALE); a[3]=(short)bfbits(f0.w*QSCALE);
      a[4]=(short)bfbits(f1.x*QSCALE); a[5]=(short)bfbits(f1.y*QSCALE);
      a[6]=(short)bfbits(f1.z*QSCALE); a[7]=(short)bfbits(f1.w*QSCALE);
      aq[s] = a;
    }
  }

  float mrun[4], lp[4];                 // exp2-domain running max, lane-partial sums
  f32x4 o[4] = {};
#pragma unroll
  for (int r = 0; r < 4; ++r) { mrun[r] = -1e30f; lp[r] = 0.0f; }

  auto STAGEK = [&](int b, int slot, int t) {
    const size_t toff = ((size_t)(bh * 32 + t) * 8) * 512;
#pragma unroll
    for (int i = 0; i < 2; ++i) {
      const int f = 2 * w + i;
      GL16(&Kf[toff + (size_t)f * 512 + lane * 8], &Kbuf[b][slot][f * 512]);
    }
  };
  auto STAGEV = [&](int slot, int t) {
    const size_t toff = ((size_t)(bh * 32 + t) * 8) * 512;
#pragma unroll
    for (int i = 0; i < 2; ++i) {
      const int f = 2 * w + i;
      GL16(&Vf[toff + (size_t)f * 512 + lane * 8], &Vbuf[slot][f * 512]);
    }
  };

  // P bounce via half-tiles (same-wave in-order DS; 1.25KB/wave) + PV
  auto PV = [&](const float sv[4][4], int slot, int smax) {
    short8 pa[2];
#pragma unroll
    for (int h = 0; h < 2; ++h)
      if (h <= smax) {
#pragma unroll
        for (int nt2 = 0; nt2 < 2; ++nt2)
#pragma unroll
          for (int r = 0; r < 4; ++r)
            Pw[(g * 4 + r) * 40 + nt2 * 16 + q15] = bfbits(sv[2 * h + nt2][r]);
        pa[h] = *(short8*)&Pw[q15 * 40 + g * 8];
      }
#pragma unroll
    for (int s = 0; s < 2; ++s)
      if (s <= smax)
#pragma unroll
        for (int nt = 0; nt < 4; ++nt) {
          short8 bfr = *(const short8*)&Vbuf[slot][(nt * 2 + s) * 512 + lane * 8];
          o[nt] = MFMA16(pa[s], bfr, o[nt]);
        }
  };

  auto SOFTMAX2 = [&](float svA[4][4], float svB[4][4]) {
    float lmax[4];
#pragma unroll
    for (int r = 0; r < 4; ++r) {
      float a = fmaxf(fmaxf(svA[0][r], svA[1][r]), fmaxf(svA[2][r], svA[3][r]));
      float b = fmaxf(fmaxf(svB[0][r], svB[1][r]), fmaxf(svB[2][r], svB[3][r]));
      lmax[r] = fmaxf(a, b);
    }
    const bool fast = __all((lmax[0] <= mrun[0] + THR) & (lmax[1] <= mrun[1] + THR) &
                            (lmax[2] <= mrun[2] + THR) & (lmax[3] <= mrun[3] + THR));
    if (!fast) {
#pragma unroll
      for (int r = 0; r < 4; ++r) {
        float mx = lmax[r];
        mx = fmaxf(mx, __shfl_xor(mx, 1));
        mx = fmaxf(mx, __shfl_xor(mx, 2));
        mx = fmaxf(mx, __shfl_xor(mx, 4));
        mx = fmaxf(mx, __shfl_xor(mx, 8));
        const float mn = fmaxf(mrun[r], mx);
        const float alpha = EXP2(mrun[r] - mn);
        mrun[r] = mn;
        lp[r] *= alpha;
        o[0][r] *= alpha; o[1][r] *= alpha; o[2][r] *= alpha; o[3][r] *= alpha;
      }
    }
#pragma unroll
    for (int nt = 0; nt < 4; ++nt)
#pragma unroll
      for (int r = 0; r < 4; ++r) {
        svA[nt][r] = EXP2(svA[nt][r] - mrun[r]);
        svB[nt][r] = EXP2(svB[nt][r] - mrun[r]);
      }
#pragma unroll
    for (int r = 0; r < 4; ++r)
      lp[r] += ((svA[0][r] + svA[1][r]) + (svA[2][r] + svA[3][r])) +
               ((svB[0][r] + svB[1][r]) + (svB[2][r] + svB[3][r]));
  };

  // ---- PAIRF: straight-line full pair (hot path) ----
  auto PAIRF = [&](int t, int cur) {
    const int jbA = jb0 + 4 * t;
    const int jbB = jbA + 4;

    short8 peA[2][5], peB[2][5];
#pragma unroll
    for (int s = 0; s < 2; ++s)
#pragma unroll
      for (int uu = 0; uu < 5; ++uu) {
        peA[s][uu] = *(const short8*)&PEf[((size_t)(jbA + uu) * 2 + s) * 512 + lane * 8];
        peB[s][uu] = *(const short8*)&PEf[((size_t)(jbB + uu) * 2 + s) * 512 + lane * 8];
      }

    f32x4 qkA[4] = {}, qkB[4] = {};
#pragma unroll
    for (int s = 0; s < 2; ++s)
#pragma unroll
      for (int nt = 0; nt < 4; ++nt) {
        short8 ba = *(const short8*)&Kbuf[cur][0][(nt * 2 + s) * 512 + lane * 8];
        qkA[nt] = MFMA16(aq[s], ba, qkA[nt]);
        short8 bb = *(const short8*)&Kbuf[cur][1][(nt * 2 + s) * 512 + lane * 8];
        qkB[nt] = MFMA16(aq[s], bb, qkB[nt]);
      }

    f32x4 evA[5] = {};
#pragma unroll
    for (int s = 0; s < 2; ++s)
#pragma unroll
      for (int uu = 0; uu < 5; ++uu) evA[uu] = MFMA16(aq[s], peA[s][uu], evA[uu]);

    float svA[4][4], svB[4][4];
#pragma unroll
    for (int nt = 0; nt < 4; ++nt)
#pragma unroll
      for (int r = 0; r < 4; ++r) {
        const int rw = g * 4 + r;
        const int srcLane = (lane & 48) | ((q15 + 15 - rw) & 15);
        const bool cond = (((q15 + rw + 1) & 15) > rw);
        const float sel = cond ? evA[nt + 1][r] : evA[nt][r];
        svA[nt][r] = qkA[nt][r] + __shfl(sel, srcLane, 64);
      }

    f32x4 evB[5] = {};
#pragma unroll
    for (int s = 0; s < 2; ++s)
#pragma unroll
      for (int uu = 0; uu < 5; ++uu) evB[uu] = MFMA16(aq[s], peB[s][uu], evB[uu]);

#pragma unroll
    for (int nt = 0; nt < 4; ++nt)
#pragma unroll
      for (int r = 0; r < 4; ++r) {
        const int rw = g * 4 + r;
        const int srcLane = (lane & 48) | ((q15 + 15 - rw) & 15);
        const bool cond = (((q15 + rw + 1) & 15) > rw);
        const float sel = cond ? evB[nt + 1][r] : evB[nt][r];
        svB[nt][r] = qkB[nt][r] + __shfl(sel, srcLane, 64);
      }

    SOFTMAX2(svA, svB);
    asm volatile("s_waitcnt vmcnt(0)" ::: "memory");   // Vbuf (this pair) resident
    PV(svA, 0, 1);
    PV(svB, 1, 1);
  };

  // ---- PAIRD: last pair of the diag chunk (B-tile diagonal) ----
  auto PAIRD = [&](int t, int cur) {
    const int jbA = jb0 + 4 * t;
    const int jbB = jbA + 4;
    const int ntmaxB = w;
    const int u5B = w + 2;
    const int smaxB = w >> 1;

    short8 peA[2][5], peB[2][5];
#pragma unroll
    for (int s = 0; s < 2; ++s)
#pragma unroll
      for (int uu = 0; uu < 5; ++uu) {
        peA[s][uu] = *(const short8*)&PEf[((size_t)(jbA + uu) * 2 + s) * 512 + lane * 8];
        if (uu < u5B)
          peB[s][uu] = *(const short8*)&PEf[((size_t)(jbB + uu) * 2 + s) * 512 + lane * 8];
      }

    f32x4 qkA[4] = {}, qkB[4] = {};
#pragma unroll
    for (int s = 0; s < 2; ++s)
#pragma unroll
      for (int nt = 0; nt < 4; ++nt) {
        short8 ba = *(const short8*)&Kbuf[cur][0][(nt * 2 + s) * 512 + lane * 8];
        qkA[nt] = MFMA16(aq[s], ba, qkA[nt]);
        if (nt <= ntmaxB) {
          short8 bb = *(const short8*)&Kbuf[cur][1][(nt * 2 + s) * 512 + lane * 8];
          qkB[nt] = MFMA16(aq[s], bb, qkB[nt]);
        }
      }

    f32x4 evA[5] = {};
#pragma unroll
    for (int s = 0; s < 2; ++s)
#pragma unroll
      for (int uu = 0; uu < 5; ++uu) evA[uu] = MFMA16(aq[s], peA[s][uu], evA[uu]);

    float svA[4][4], svB[4][4];
#pragma unroll
    for (int nt = 0; nt < 4; ++nt)
#pragma unroll
      for (int r = 0; r < 4; ++r) {
        const int rw = g * 4 + r;
        const int srcLane = (lane & 48) | ((q15 + 15 - rw) & 15);
        const bool cond = (((q15 + rw + 1) & 15) > rw);
        const float sel = cond ? evA[nt + 1][r] : evA[nt][r];
        svA[nt][r] = qkA[nt][r] + __shfl(sel, srcLane, 64);
        svB[nt][r] = -1e30f;
      }

    f32x4 evB[5] = {};
#pragma unroll
    for (int s = 0; s < 2; ++s)
#pragma unroll
      for (int uu = 0; uu < 5; ++uu)
        if (uu < u5B) evB[uu] = MFMA16(aq[s], peB[s][uu], evB[uu]);

#pragma unroll
    for (int nt = 0; nt < 4; ++nt)
      if (nt <= ntmaxB) {
#pragma unroll
        for (int r = 0; r < 4; ++r) {
          const int rw = g * 4 + r;
          const int srcLane = (lane & 48) | ((q15 + 15 - rw) & 15);
          const bool cond = (((q15 + rw + 1) & 15) > rw);
          const float sel = cond ? evB[nt + 1][r] : evB[nt][r];
          const float er = __shfl(sel, srcLane, 64);
          const int li = nt * 16 + q15;
          const bool masked = (li > w * 16 + rw);
          svB[nt][r] = masked ? -1e30f : (qkB[nt][r] + er);
        }
      }

    SOFTMAX2(svA, svB);
    asm volatile("s_waitcnt vmcnt(0)" ::: "memory");
    PV(svA, 0, 1);
    PV(svB, 1, smaxB);
  };

  // ---- SINGLE: odd-remainder tile (may be diagonal) ----
  auto SINGLE = [&](int t, int cur, bool diag) {
    const int jb = jb0 + 4 * t;
    const int ntmax = diag ? w : 3;
    const int u5 = diag ? (w + 2) : 5;
    const int smax = diag ? (w >> 1) : 1;

    short8 pe[2][5];
#pragma unroll
    for (int s = 0; s < 2; ++s)
#pragma unroll
      for (int uu = 0; uu < 5; ++uu)
        if (uu < u5)
          pe[s][uu] = *(const short8*)&PEf[((size_t)(jb + uu) * 2 + s) * 512 + lane * 8];

    f32x4 qk[4] = {};
#pragma unroll
    for (int s = 0; s < 2; ++s)
#pragma unroll
      for (int nt = 0; nt < 4; ++nt)
        if (nt <= ntmax) {
          short8 bfr = *(const short8*)&Kbuf[cur][0][(nt * 2 + s) * 512 + lane * 8];
          qk[nt] = MFMA16(aq[s], bfr, qk[nt]);
        }
    f32x4 ev[5] = {};
#pragma unroll
    for (int s = 0; s < 2; ++s)
#pragma unroll
      for (int uu = 0; uu < 5; ++uu)
        if (uu < u5) ev[uu] = MFMA16(aq[s], pe[s][uu], ev[uu]);

    float sv[4][4];
#pragma unroll
    for (int nt = 0; nt < 4; ++nt)
#pragma unroll
      for (int r = 0; r < 4; ++r) sv[nt][r] = -1e30f;
#pragma unroll
    for (int nt = 0; nt < 4; ++nt)
      if (nt <= ntmax) {
#pragma unroll
        for (int r = 0; r < 4; ++r) {
          const int rw = g * 4 + r;
          const int srcLane = (lane & 48) | ((q15 + 15 - rw) & 15);
          const bool cond = (((q15 + rw + 1) & 15) > rw);
          const float sel = cond ? ev[nt + 1][r] : ev[nt][r];
          const float er = __shfl(sel, srcLane, 64);
          const int li = nt * 16 + q15;
          const bool masked = diag && (li > w * 16 + rw);
          sv[nt][r] = masked ? -1e30f : (qk[nt][r] + er);
        }
      }

    float lmax[4];
#pragma unroll
    for (int r = 0; r < 4; ++r)
      lmax[r] = fmaxf(fmaxf(sv[0][r], sv[1][r]), fmaxf(sv[2][r], sv[3][r]));
    const bool fast = __all((lmax[0] <= mrun[0] + THR) & (lmax[1] <= mrun[1] + THR) &
                            (lmax[2] <= mrun[2] + THR) & (lmax[3] <= mrun[3] + THR));
    if (!fast) {
#pragma unroll
      for (int r = 0; r < 4; ++r) {
        float mx = lmax[r];
        mx = fmaxf(mx, __shfl_xor(mx, 1));
        mx = fmaxf(mx, __shfl_xor(mx, 2));
        mx = fmaxf(mx, __shfl_xor(mx, 4));
        mx = fmaxf(mx, __shfl_xor(mx, 8));
        const float mn = fmaxf(mrun[r], mx);
        const float alpha = EXP2(mrun[r] - mn);
        mrun[r] = mn;
        lp[r] *= alpha;
        o[0][r] *= alpha; o[1][r] *= alpha; o[2][r] *= alpha; o[3][r] *= alpha;
      }
    }
#pragma unroll
    for (int nt = 0; nt < 4; ++nt)
#pragma unroll
      for (int r = 0; r < 4; ++r)
        sv[nt][r] = EXP2(sv[nt][r] - mrun[r]);
#pragma unroll
    for (int r = 0; r < 4; ++r)
      lp[r] += (sv[0][r] + sv[1][r]) + (sv[2][r] + sv[3][r]);
    asm volatile("s_waitcnt vmcnt(0)" ::: "memory");
    PV(sv, 0, smax);
  };

  // ---- main loop: K dbuf prefetch, V staged in-body (single buffer), 1 barrier/pair ----
  {
    int cur = 0;
    int t = t0;
    const int n0 = (t1 - t0 >= 2) ? 2 : 1;
    STAGEK(0, 0, t0);
    if (n0 == 2) STAGEK(0, 1, t0 + 1);
    __syncthreads();
    while (t < t1) {
      const int n = (t1 - t >= 2) ? 2 : 1;
      STAGEV(0, t);
      if (n == 2) STAGEV(1, t + 1);
      const int rem = t1 - (t + n);
      const int nn = (rem >= 2) ? 2 : rem;
      if (nn > 0) {
        STAGEK(cur ^ 1, 0, t + n);
        if (nn == 2) STAGEK(cur ^ 1, 1, t + n + 1);
      }
      if (n == 2) {
        if (t + 1 == mt) PAIRD(t, cur);
        else PAIRF(t, cur);
      } else {
        SINGLE(t, cur, (t == mt));
      }
      if (nn > 0) __syncthreads();
      cur ^= 1;
      t += n;
    }
  }

  // ---- epilogue: one-time butterfly of lane-partial sums ----
  float lr[4];
#pragma unroll
  for (int r = 0; r < 4; ++r) {
    float s = lp[r];
    s += __shfl_xor(s, 1);
    s += __shfl_xor(s, 2);
    s += __shfl_xor(s, 4);
    s += __shfl_xor(s, 8);
    lr[r] = s;
  }

  if (nch == 1) {
#pragma unroll
    for (int nt = 0; nt < 4; ++nt)
#pragma unroll
      for (int r = 0; r < 4; ++r) {
        const int m = m0w + g * 4 + r;
        Ob[(size_t)m * Dn + nt * 16 + q15] = o[nt][r] / lr[r];
      }
  } else {
    float* ps = Part + ((size_t)bh * SLOTS_PER_HEAD + part_offs(mt) + chunk) * PART_SLOT;
#pragma unroll
    for (int nt = 0; nt < 4; ++nt)
#pragma unroll
      for (int r = 0; r < 4; ++r)
        ps[(w * 16 + g * 4 + r) * 64 + nt * 16 + q15] = o[nt][r];
#pragma unroll
    for (int r = 0; r < 4; ++r)
      if (q15 == g * 4 + r) {
        ps[4096 + w * 16 + q15] = mrun[r];     // exp2-domain max
        ps[4160 + w * 16 + q15] = lr[r];
      }
  }
}

// ---------------- combine: merge 2-4 chunk partials (exp2-domain maxima) ----------------

__launch_bounds__(256, 4)
__global__ void combine_parts(const float* __restrict__ Part, float* __restrict__ Og) {
  const int bid = blockIdx.x;
  const int bh = bid & 15;
  const int mt = 8 + (bid >> 4);
  const int nch = (mt + 8) >> 3;
  const float* base = Part + ((size_t)bh * SLOTS_PER_HEAD + part_offs(mt)) * PART_SLOT;
  const int tid = threadIdx.x;
  const int row = tid >> 2;
  const int qc = (tid & 3) * 16;

  float mstar = -1e30f;
#pragma unroll
  for (int cc = 0; cc < 4; ++cc)
    if (cc < nch) mstar = fmaxf(mstar, base[cc * PART_SLOT + 4096 + row]);
  float lsum = 0.f;
  f32x4 acc0 = {}, acc1 = {}, acc2 = {}, acc3 = {};
#pragma unroll
  for (int cc = 0; cc < 4; ++cc)
    if (cc < nch) {
      const float* ps = base + cc * PART_SLOT;
      const float sc = EXP2(ps[4096 + row] - mstar);   // already log2-domain
      lsum += ps[4160 + row] * sc;
      const f32x4* op = (const f32x4*)&ps[row * 64 + qc];
      acc0 += op[0] * sc; acc1 += op[1] * sc; acc2 += op[2] * sc; acc3 += op[3] * sc;
    }
  const float inv = 1.f / lsum;
  float* dst = Og + ((size_t)bh * Mn + mt * 64 + row) * Dn + qc;
  *(f32x4*)&dst[0]  = acc0 * inv;
  *(f32x4*)&dst[4]  = acc1 * inv;
  *(f32x4*)&dst[8]  = acc2 * inv;
  *(f32x4*)&dst[12] = acc3 * inv;
}

// ---------------- fallback (round-1 kernel, passed @118us, no ws needed) ----------------

constexpr int ESTRIDE = 84;

__launch_bounds__(256, 2)
__global__ void stair_attn_fb(const float* __restrict__ Qg,
                              const float* __restrict__ Kg,
                              const float* __restrict__ Vg,
                              const float* __restrict__ PEg,
                              float* __restrict__ Og) {
  __shared__ __align__(16) unsigned short Kb[64 * 64];
  __shared__ __align__(16) unsigned short Vt[64 * 64];
  __shared__ __align__(16) unsigned short Pb[128 * 64];
  __shared__ __align__(16) float Elds[4 * 16 * ESTRIDE];
  __shared__ __align__(16) unsigned short Plds[4 * 16 * 64];

  const int tid = threadIdx.x;
  const int w = tid >> 6;
  const int lane = tid & 63;
  const int g = lane >> 4;
  const int q15 = lane & 15;

  const int bid = blockIdx.x;
  const int bh = bid & 15;
  const int jid = bid >> 4;
  const int mt = (jid < 16) ? (2 * jid) : (63 - 2 * jid);
  const int m0 = mt * 64;

  const float* Qb = Qg + (size_t)bh * Mn * Dn;
  const float* Kbase = Kg + (size_t)bh * Mn * Dn;
  const float* Vbase = Vg + (size_t)bh * Mn * Dn;
  float* Ob = Og + (size_t)bh * Mn * Dn;

  short8 aq[2];
  {
    const float* qp = Qb + (size_t)(m0 + 16 * w + q15) * Dn;
#pragma unroll
    for (int s = 0; s < 2; ++s) {
      const float4* p = (const float4*)(qp + s * 32 + g * 8);
      float4 f0 = p[0], f1 = p[1];
      short8 a;
      a[0]=(short)bfbits(f0.x); a[1]=(short)bfbits(f0.y); a[2]=(short)bfbits(f0.z); a[3]=(short)bfbits(f0.w);
      a[4]=(short)bfbits(f1.x); a[5]=(short)bfbits(f1.y); a[6]=(short)bfbits(f1.z); a[7]=(short)bfbits(f1.w);
      aq[s] = a;
    }
  }

  float mrun[4], lrun[4];
  f32x4 o[4] = {};
#pragma unroll
  for (int r = 0; r < 4; ++r) { mrun[r] = -1e30f; lrun[r] = 0.0f; }

  const int ntiles = mt + 1;
  const int dso = g * 8;

  for (int t = 0; t < ntiles; ++t) {
    const int l0 = t * 64;
    __syncthreads();
    {
      const int l = tid >> 2;
      const int dq = (tid & 3) * 16;
      const float* kp = Kbase + (size_t)(l0 + l) * Dn + dq;
      short8 u0, u1;
      {
        float4 f = ((const float4*)kp)[0];
        u0[0]=(short)bfbits(f.x); u0[1]=(short)bfbits(f.y); u0[2]=(short)bfbits(f.z); u0[3]=(short)bfbits(f.w);
        f = ((const float4*)kp)[1];
        u0[4]=(short)bfbits(f.x); u0[5]=(short)bfbits(f.y); u0[6]=(short)bfbits(f.z); u0[7]=(short)bfbits(f.w);
        f = ((const float4*)kp)[2];
        u1[0]=(short)bfbits(f.x); u1[1]=(short)bfbits(f.y); u1[2]=(short)bfbits(f.z); u1[3]=(short)bfbits(f.w);
        f = ((const float4*)kp)[3];
        u1[4]=(short)bfbits(f.x); u1[5]=(short)bfbits(f.y); u1[6]=(short)bfbits(f.z); u1[7]=(short)bfbits(f.w);
      }
      const int swz = (l & 7) << 3;
      *(short8*)&Kb[(l * 64 + dq) ^ swz] = u0;
      *(short8*)&Kb[(l * 64 + dq + 8) ^ swz] = u1;
    }
    {
      const int lrow = lane;
      const int ds = w * 16;
      const float* vp = Vbase + (size_t)(l0 + lrow) * Dn + ds;
#pragma unroll
      for (int i = 0; i < 4; ++i) {
        float4 f = ((const float4*)vp)[i];
        int c0 = ds + 4 * i;
        Vt[((c0 + 0) * 64 + lrow) ^ (((c0 + 0) & 7) << 3)] = bfbits(f.x);
        Vt[((c0 + 1) * 64 + lrow) ^ (((c0 + 1) & 7) << 3)] = bfbits(f.y);
        Vt[((c0 + 2) * 64 + lrow) ^ (((c0 + 2) & 7) << 3)] = bfbits(f.z);
        Vt[((c0 + 3) * 64 + lrow) ^ (((c0 + 3) & 7) << 3)] = bfbits(f.w);
      }
    }
    {
      const int d = lane;
      const int cc = w * 32;
      const int cb = (2048 - 64) - m0 + l0;
      const float* pp = PEg + (size_t)d * LIMn + (cb + cc);
      if (cb + cc + 31 < LIMn) {
#pragma unroll
        for (int i = 0; i < 8; ++i) {
          float4 f = ((const float4*)pp)[i];
          int c0 = cc + 4 * i;
          Pb[((c0 + 0) * 64 + d) ^ (((c0 + 0) & 7) << 3)] = bfbits(f.x);
          Pb[((c0 + 1) * 64 + d) ^ (((c0 + 1) & 7) << 3)] = bfbits(f.y);
          Pb[((c0 + 2) * 64 + d) ^ (((c0 + 2) & 7) << 3)] = bfbits(f.z);
          Pb[((c0 + 3) * 64 + d) ^ (((c0 + 3) & 7) << 3)] = bfbits(f.w);
        }
      } else {
        for (int i = 0; i < 32; ++i) {
          int cabs = cb + cc + i;
          float f = (cabs < LIMn) ? pp[i] : 0.0f;
          int c0 = cc + i;
          Pb[(c0 * 64 + d) ^ ((c0 & 7) << 3)] = bfbits(f);
        }
      }
    }
    __syncthreads();

    f32x4 qk[4] = {};
#pragma unroll
    for (int s = 0; s < 2; ++s)
#pragma unroll
      for (int nt = 0; nt < 4; ++nt) {
        int l = nt * 16 + q15;
        short8 b = *(short8*)&Kb[(l * 64 + s * 32 + dso) ^ ((l & 7) << 3)];
        qk[nt] = MFMA16(aq[s], b, qk[nt]);
      }

    f32x4 ev[5] = {};
    const int ntb = 3 - w;
#pragma unroll
    for (int s = 0; s < 2; ++s)
#pragma unroll
      for (int u5 = 0; u5 < 5; ++u5) {
        int c = (ntb + u5) * 16 + q15;
        short8 b = *(short8*)&Pb[(c * 64 + s * 32 + dso) ^ ((c & 7) << 3)];
        ev[u5] = MFMA16(aq[s], b, ev[u5]);
      }
    float* Ew = Elds + w * 16 * ESTRIDE;
#pragma unroll
    for (int u5 = 0; u5 < 5; ++u5)
#pragma unroll
      for (int r = 0; r < 4; ++r)
        Ew[(g * 4 + r) * ESTRIDE + u5 * 16 + q15] = ev[u5][r];

    const bool diag = (t == ntiles - 1);
    float sv[4][4];
#pragma unroll
    for (int nt = 0; nt < 4; ++nt) {
      int li = nt * 16 + q15;
#pragma unroll
      for (int r = 0; r < 4; ++r) {
        int rw = g * 4 + r;
        float eread = Ew[rw * ESTRIDE + (15 - rw + li)];
        bool masked = diag && (li > (16 * w + rw));
        sv[nt][r] = masked ? -1e30f : (qk[nt][r] + eread) * 0.125f;
      }
    }

    float mnew[4], alpha[4];
#pragma unroll
    for (int r = 0; r < 4; ++r) {
      float mx = fmaxf(fmaxf(sv[0][r], sv[1][r]), fmaxf(sv[2][r], sv[3][r]));
      mx = fmaxf(mx, __shfl_xor(mx, 1));
      mx = fmaxf(mx, __shfl_xor(mx, 2));
      mx = fmaxf(mx, __shfl_xor(mx, 4));
      mx = fmaxf(mx, __shfl_xor(mx, 8));
      float mn = fmaxf(mrun[r], mx);
      alpha[r] = exp2f((mrun[r] - mn) * 1.44269504f);
      mnew[r] = mn;
      mrun[r] = mn;
    }
    float pexp[4][4];
#pragma unroll
    for (int nt = 0; nt < 4; ++nt)
#pragma unroll
      for (int r = 0; r < 4; ++r)
        pexp[nt][r] = exp2f((sv[nt][r] - mnew[r]) * 1.44269504f);
#pragma unroll
    for (int r = 0; r < 4; ++r) {
      float sum = (pexp[0][r] + pexp[1][r]) + (pexp[2][r] + pexp[3][r]);
      sum += __shfl_xor(sum, 1);
      sum += __shfl_xor(sum, 2);
      sum += __shfl_xor(sum, 4);
      sum += __shfl_xor(sum, 8);
      lrun[r] = lrun[r] * alpha[r] + sum;
      o[0][r] *= alpha[r];
      o[1][r] *= alpha[r];
      o[2][r] *= alpha[r];
      o[3][r] *= alpha[r];
    }

    unsigned short* Pw = Plds + w * 16 * 64;
#pragma unroll
    for (int nt = 0; nt < 4; ++nt)
#pragma unroll
      for (int r = 0; r < 4; ++r) {
        int rw = g * 4 + r;
        Pw[(rw * 64 + nt * 16 + q15) ^ ((rw & 7) << 3)] = bfbits(pexp[nt][r]);
      }
    short8 pa[2];
#pragma unroll
    for (int s = 0; s < 2; ++s)
      pa[s] = *(short8*)&Pw[(q15 * 64 + s * 32 + dso) ^ ((q15 & 7) << 3)];

#pragma unroll
    for (int s = 0; s < 2; ++s)
#pragma unroll
      for (int nt = 0; nt < 4; ++nt) {
        int d = nt * 16 + q15;
        short8 b = *(short8*)&Vt[(d * 64 + s * 32 + dso) ^ ((d & 7) << 3)];
        o[nt] = MFMA16(pa[s], b, o[nt]);
      }
  }

#pragma unroll
  for (int nt = 0; nt < 4; ++nt)
#pragma unroll
    for (int r = 0; r < 4; ++r) {
      int m = m0 + 16 * w + g * 4 + r;
      Ob[(size_t)m * Dn + nt * 16 + q15] = o[nt][r] / lrun[r];
    }
}

// ---------------- launch ----------------

extern "C" void kernel_launch(void* const* d_in, const int* in_sizes, int n_in,
                              void* d_out, int out_size, void* d_ws, size_t ws_size,
                              hipStream_t stream) {
  (void)in_sizes; (void)n_in; (void)out_size;
  const float* Q  = (const float*)d_in[0];
  const float* K  = (const float*)d_in[1];
  const float* V  = (const float*)d_in[2];
  const float* PE = (const float*)d_in[3];
  float* Out = (float*)d_out;

  const size_t szK = KF_SHORTS * sizeof(unsigned short);              // 4 MB
  const size_t szV = szK;                                              // 4 MB
  const size_t szP = PEF_SHORTS * sizeof(unsigned short);              // 264 KB
  const size_t szPart = (size_t)BH * SLOTS_PER_HEAD * PART_SLOT * 4;   // 19.5 MB
  const size_t need1 = szK + szV + szP;
  const size_t need2 = need1 + szPart;

  if (ws_size >= need1) {
    unsigned short* Kf  = (unsigned short*)d_ws;
    unsigned short* Vf  = (unsigned short*)((char*)d_ws + szK);
    unsigned short* PEf = (unsigned short*)((char*)d_ws + szK + szV);
    float* Part = (float*)((char*)d_ws + need1);

    hipLaunchKernelGGL(prep_all, dim3(512 + 33), dim3(256), 0, stream, K, V, PE, Kf, Vf, PEf);
    if (ws_size >= need2) {
      hipLaunchKernelGGL(stair_main, dim3(BH * 80), dim3(256), 0, stream,
                         Q, Kf, Vf, PEf, Out, Part, 1);
      hipLaunchKernelGGL(combine_parts, dim3(BH * 24), dim3(256), 0, stream, Part, Out);
    } else {
      hipLaunchKernelGGL(stair_main, dim3(512), dim3(256), 0, stream,
                         Q, Kf, Vf, PEf, Out, (float*)d_ws, 0);
    }
  } else {
    hipLaunchKernelGGL(stair_attn_fb, dim3(512), dim3(256), 0, stream, Q, K, V, PE, Out);
  }
}